// Round 1
// baseline (621.847 us; speedup 1.0000x reference)
//
#include <hip/hip_runtime.h>

#define B_ 8
#define N_ 16384
#define F_ 6
#define M_ 128
#define K_ 16
#define D_ 768

typedef unsigned short u16;
typedef unsigned int u32;
typedef unsigned long long u64;
typedef __attribute__((ext_vector_type(8))) short short8;
typedef __attribute__((ext_vector_type(4))) float f32x4;
typedef __attribute__((ext_vector_type(2))) float f32x2;

__device__ __forceinline__ u16 f2bf(float f){
  union { float f; u32 i; } v; v.f = f;
  u32 x = v.i;
  u32 r = x + 0x7FFFu + ((x >> 16) & 1u);
  return (u16)(r >> 16);
}

// async 16B global->LDS (dest = wave-uniform base + lane*16)
__device__ __forceinline__ void ld_g2l(const u16* g, u16* l){
  __builtin_amdgcn_global_load_lds((const __attribute__((address_space(1))) u32*)g,
                                   (__attribute__((address_space(3))) u32*)l, 16, 0, 0);
}

// ---------------- all weights f32 -> bf16 transposed [n][k], ONE kernel ----------------
__global__ __launch_bounds__(256) void conv_all(const float* __restrict__ W1,
                                                const float* __restrict__ W2,
                                                const float* __restrict__ W3,
                                                const float* __restrict__ Wn0,
                                                const float* __restrict__ Wn1,
                                                u16* __restrict__ Wb){
  __shared__ u16 tile[64][65];
  int blk = blockIdx.x;
  const float* W; u16* WT; int K, N, lb;
  if      (blk < 32)  { W = W1;  WT = Wb;           K = 256; N = 512; lb = blk; }
  else if (blk < 128) { W = W2;  WT = Wb + 131072;  K = 512; N = 768; lb = blk - 32; }
  else if (blk < 272) { W = W3;  WT = Wb + 524288;  K = 768; N = 768; lb = blk - 128; }
  else if (blk < 416) { W = Wn0; WT = Wb + 1114112; K = 768; N = 768; lb = blk - 272; }
  else                { W = Wn1; WT = Wb + 1703936; K = 768; N = 768; lb = blk - 416; }
  int tiles_n = N >> 6;
  int tk = lb / tiles_n, tn = lb % tiles_n;
  int k0 = tk << 6, n0 = tn << 6;
  int t = threadIdx.x;
#pragma unroll
  for (int q = 0; q < 16; q++){
    int idx = q * 256 + t;
    int kk = idx >> 6, nn = idx & 63;
    tile[kk][nn] = f2bf(W[(size_t)(k0 + kk) * N + n0 + nn]);
  }
  __syncthreads();
#pragma unroll
  for (int q = 0; q < 16; q++){
    int idx = q * 256 + t;
    int nn = idx >> 6, kk = idx & 63;
    WT[(size_t)(n0 + nn) * K + k0 + kk] = tile[kk][nn];
  }
}

// ---------------- zero the cross-block FPS sync slots (per launch, graph-safe) ----------------
__global__ __launch_bounds__(256) void zero_keys(u64* __restrict__ keys){
  keys[(size_t)blockIdx.x * 256 + threadIdx.x] = 0ull;
}

// ---------------- multi-CU FPS: 8 blocks/batch, step-indexed lock-free sync ----------------
// Each block owns 2048 points (registers). Per step: local argmax -> publish u64 key
// (dist_bits+1)<<32 | (N-1-idx)  [monotone in (value, lowest-index tiebreak)] to an
// agent-scope slot; all blocks poll the 8 slots of their batch (step-indexed -> no reset).
#define FG 8     // blocks per batch
#define FJ 4     // f32x2 pairs per thread: 2048 / (2*256)
__global__ __launch_bounds__(256) void fps_multi(const float* __restrict__ coords,
                                                 float* __restrict__ cent,
                                                 u64* __restrict__ keys){
#pragma clang fp contract(off)
  __shared__ float s_wv[2][4];
  __shared__ int   s_wi[2][4];
  int blk = blockIdx.x;
  int b = blk >> 3, g = blk & 7;
  int t = threadIdx.x;
  int lane = t & 63, wave = t >> 6;
  const float* cb = coords + (size_t)b * N_ * 5;
  int pbase = g << 11;                          // g * 2048
  f32x2 px[FJ], py[FJ], pz[FJ], pw[FJ], md[FJ];
#pragma unroll
  for (int j = 0; j < FJ; j++){
    int p = pbase + ((t + (j << 8)) << 1);
    size_t i0 = (size_t)p * 5;
    px[j] = (f32x2){cb[i0+1], cb[i0+6]};
    py[j] = (f32x2){cb[i0+2], cb[i0+7]};
    pz[j] = (f32x2){cb[i0+3], cb[i0+8]};
    pw[j] = (f32x2){cb[i0+4], cb[i0+9]};
    md[j] = (f32x2){1e30f, 1e30f};
  }
  float cx = cb[1], cy = cb[2], cz = cb[3], ct = cb[4];
  if (g == 0 && t == 0){
    float* c0 = cent + (size_t)b * M_ * 4;
    c0[0]=cx; c0[1]=cy; c0[2]=cz; c0[3]=ct;
  }
  for (int step = 1; step < M_; step++){
    f32x2 cx2 = (f32x2){cx, cx}, cy2 = (f32x2){cy, cy};
    f32x2 cz2 = (f32x2){cz, cz}, ct2 = (f32x2){ct, ct};
    float bv = -1.0f; int bi = 1 << 30;
#pragma unroll
    for (int j = 0; j < FJ; j++){
      f32x2 dX = px[j] - cx2;
      f32x2 dY = py[j] - cy2;
      f32x2 s = dX*dX + dY*dY;               // per-point numpy order (contract off)
      f32x2 dZ = pz[j] - cz2;
      s = s + dZ*dZ;
      f32x2 dW = pw[j] - ct2;
      s = s + dW*dW;
      f32x2 m = md[j];
      m[0] = (s[0] < m[0]) ? s[0] : m[0];
      m[1] = (s[1] < m[1]) ? s[1] : m[1];
      md[j] = m;
      int i0 = pbase + ((t + (j << 8)) << 1);
      if (m[0] > bv){ bv = m[0]; bi = i0; }        // ascending-index first-max
      if (m[1] > bv){ bv = m[1]; bi = i0 + 1; }
    }
#pragma unroll
    for (int off = 32; off > 0; off >>= 1){
      float ov = __shfl_down(bv, off);
      int oi = __shfl_down(bi, off);
      if (ov > bv || (ov == bv && oi < bi)){ bv = ov; bi = oi; }
    }
    int par = step & 1;
    if (lane == 0){ s_wv[par][wave] = bv; s_wi[par][wave] = bi; }
    __syncthreads();                               // only barrier per step
    u64* kb = keys + (((size_t)step << 3) + b) * 8;
    if (t == 0){
      float fv = s_wv[par][0]; int fi = s_wi[par][0];
#pragma unroll
      for (int w = 1; w < 4; w++){
        float wv = s_wv[par][w]; int wi = s_wi[par][w];
        if (wv > fv || (wv == fv && wi < fi)){ fv = wv; fi = wi; }
      }
      union { float f; u32 i; } vb; vb.f = fv;
      u64 key = ((u64)(vb.i + 1u) << 32) | (u32)(N_ - 1 - fi);
      __hip_atomic_store(&kb[g], key, __ATOMIC_RELAXED, __HIP_MEMORY_SCOPE_AGENT);
    }
    // poll the 8 slots of this (step, batch); lane i watches slot i&7 (one 64B line)
    u64 k = __hip_atomic_load(&kb[lane & 7], __ATOMIC_RELAXED, __HIP_MEMORY_SCOPE_AGENT);
    while (k == 0ull){
      __builtin_amdgcn_s_sleep(1);
      k = __hip_atomic_load(&kb[lane & 7], __ATOMIC_RELAXED, __HIP_MEMORY_SCOPE_AGENT);
    }
#pragma unroll
    for (int off = 1; off < 8; off <<= 1){
      u64 ok = __shfl_xor(k, off);
      if (ok > k) k = ok;
    }
    int widx = N_ - 1 - (int)(k & 0xffffffffu);
    size_t wbase = (size_t)widx * 5;
    cx = cb[wbase+1]; cy = cb[wbase+2]; cz = cb[wbase+3]; ct = cb[wbase+4];
    if (g == 0 && t == 0){
      float* cr = cent + ((size_t)b * M_ + step) * 4;
      cr[0]=cx; cr[1]=cy; cr[2]=cz; cr[3]=ct;
    }
  }
}

// ---------------- stable rank by centroid time; relabel early; f32 outputs ----------------
__global__ __launch_bounds__(128) void rank_scatter(const float* __restrict__ cent_fps,
                                                    float* __restrict__ cent_sorted,
                                                    float* __restrict__ out,
                                                    size_t out_elems){
  int b = blockIdx.x, m = threadIdx.x;
  __shared__ float tt[M_];
  const float* row = cent_fps + ((size_t)b * M_ + m) * 4;
  float x=row[0], y=row[1], z=row[2], w=row[3];
  tt[m] = w;
  __syncthreads();
  int rank = 0;
  for (int j = 0; j < M_; j++){
    float tj = tt[j];
    if (tj < w || (tj == w && j < m)) rank++;       // stable argsort semantics
  }
  float* dst = cent_sorted + ((size_t)b * M_ + rank) * 4;
  dst[0]=x; dst[1]=y; dst[2]=z; dst[3]=w;
  size_t co = (size_t)B_ * M_ * D_ + ((size_t)b * M_ + rank) * 4;
  if (co + 3 < out_elems){
    out[co+0]=x; out[co+1]=y; out[co+2]=z; out[co+3]=w;
  }
  size_t mo = (size_t)B_ * M_ * D_ + (size_t)B_ * M_ * 4 + (size_t)b * M_ + m;
  if (mo < out_elems) out[mo] = 1.0f;              // mask = True -> 1.0f
}

// ---------------- kNN: f32, np op order, stable-min extraction ----------------
#define KNT 512
#define KPT 32
__global__ __launch_bounds__(512) void knn_kernel(const float* __restrict__ coords,
                                                  const float* __restrict__ cent,
                                                  int* __restrict__ knn){
#pragma clang fp contract(off)
  int cm = blockIdx.x;
  int b = cm >> 7;
  const float* cb = coords + (size_t)b * N_ * 5;
  int t = threadIdx.x;
  float cx=cent[cm*4+0], cy=cent[cm*4+1], cz=cent[cm*4+2], ct=cent[cm*4+3];
  float dist[KPT];
#pragma unroll
  for (int j = 0; j < KPT; j++){
    size_t i = t + j * KNT;
    float dx=cb[i*5+1]-cx, dy=cb[i*5+2]-cy, dz=cb[i*5+3]-cz, dw=cb[i*5+4]-ct;
    float d = ((dx*dx + dy*dy) + dz*dz) + dw*dw;
    dist[j] = sqrtf(d);                            // IEEE f32 sqrt = np.sqrt(f32)
  }
  __shared__ float s_wv[8];
  __shared__ int s_wi[8];
  __shared__ int s_bi;
  for (int r = 0; r < K_; r++){
    float bv = 3e38f; int bi = 1 << 30;
#pragma unroll
    for (int j = 0; j < KPT; j++){
      int i = t + j * KNT;
      float v = dist[j];
      if (v < bv){ bv = v; bi = i; }               // first-min kept
    }
#pragma unroll
    for (int off = 32; off > 0; off >>= 1){
      float ov = __shfl_down(bv, off);
      int oi = __shfl_down(bi, off);
      if (ov < bv || (ov == bv && oi < bi)){ bv = ov; bi = oi; }
    }
    if ((t & 63) == 0){ s_wv[t >> 6] = bv; s_wi[t >> 6] = bi; }
    __syncthreads();
    if (t == 0){
      float fv = s_wv[0]; int fi = s_wi[0];
      for (int w = 1; w < 8; w++){
        float wv = s_wv[w]; int wi = s_wi[w];
        if (wv < fv || (wv == fv && wi < fi)){ fv = wv; fi = wi; }
      }
      s_bi = fi;
      knn[(size_t)cm * K_ + r] = fi & (N_ - 1);
    }
    __syncthreads();
    int wi = s_bi;
#pragma unroll
    for (int j = 0; j < KPT; j++){
      if (t + j * KNT == wi) dist[j] = 3e38f;
    }
  }
}

// ---------------- gather + layer0: 32 rows/block, W0/b0/features LDS-staged ----------------
__global__ __launch_bounds__(256) void gather_l0(const float* __restrict__ feat,
                                                 const int* __restrict__ knn,
                                                 const float* __restrict__ W0,
                                                 const float* __restrict__ b0,
                                                 u16* __restrict__ h1,
                                                 int rowBase){
  __shared__ float sW[F_][256];
  __shared__ float sb[256];
  __shared__ float sfa[32][F_];
  int t = threadIdx.x;
#pragma unroll
  for (int k = 0; k < F_; k++) sW[k][t] = W0[k * 256 + t];
  sb[t] = b0[t];
  if (t < 32 * F_){
    int r = t / F_, k = t % F_;
    int grow = rowBase + blockIdx.x * 32 + r;
    int bb = grow >> 11;                          // /(M*K)=2048
    int idx = knn[grow] & (N_ - 1);
    sfa[r][k] = feat[((size_t)bb * N_ + idx) * F_ + k];
  }
  __syncthreads();
#pragma unroll 4
  for (int r = 0; r < 32; r++){
    float acc = sb[t];
#pragma unroll
    for (int k = 0; k < F_; k++) acc = fmaf(sfa[r][k], sW[k][t], acc);
    int lrow = blockIdx.x * 32 + r;
    h1[(size_t)lrow * 256 + t] = f2bf(fmaxf(acc, 0.0f));
  }
}

// ---------------- bf16 MFMA GEMM (128x128), async global->LDS staging ----------------
// Unpadded [128][32] rows (64B): dest = wave-uniform base + lane*16 (m97 layout).
template<int RELU, int OUTF32>
__global__ __launch_bounds__(256) void gemm_bf16(const u16* __restrict__ A,
                                                 const u16* __restrict__ WT,
                                                 const float* __restrict__ bias,
                                                 void* __restrict__ Cv,
                                                 int Kd, int Nd){
  __shared__ u16 As[128][32];
  __shared__ u16 Bs[128][32];
  const int t = threadIdx.x;
  const int bm = blockIdx.y << 7;
  const int bn = blockIdx.x << 7;
  const int wave = t >> 6;
  const int lane = t & 63;
  const int wm = (wave & 1) << 6;
  const int wn = (wave >> 1) << 6;
  const int lm = lane & 15;
  const int lk = (lane >> 4) << 3;
  u16* AsF = &As[0][0];
  u16* BsF = &Bs[0][0];
  const int wbase = wave << 6;               // t - lane
  f32x4 acc[4][4] = {};
  for (int k0 = 0; k0 < Kd; k0 += 32){
#pragma unroll
    for (int it = 0; it < 2; it++){
      int slot = t + (it << 8);
      int r = slot >> 2;
      int c = (slot & 3) << 3;
      int dst = (wbase + (it << 8)) << 3;    // u16 elements; +lane*16B by HW
      ld_g2l(A  + (size_t)(bm + r) * Kd + k0 + c, AsF + dst);
      ld_g2l(WT + (size_t)(bn + r) * Kd + k0 + c, BsF + dst);
    }
    __syncthreads();
    short8 af[4], bfr[4];
#pragma unroll
    for (int mt = 0; mt < 4; mt++) af[mt] = *(const short8*)&As[wm + (mt << 4) + lm][lk];
#pragma unroll
    for (int nt = 0; nt < 4; nt++) bfr[nt] = *(const short8*)&Bs[wn + (nt << 4) + lm][lk];
#pragma unroll
    for (int mt = 0; mt < 4; mt++)
#pragma unroll
      for (int nt = 0; nt < 4; nt++)
        acc[mt][nt] = __builtin_amdgcn_mfma_f32_16x16x32_bf16(af[mt], bfr[nt], acc[mt][nt], 0, 0, 0);
    __syncthreads();
  }
#pragma unroll
  for (int nt = 0; nt < 4; nt++){
    int n = bn + wn + (nt << 4) + lm;
    float bia = bias[n];
#pragma unroll
    for (int mt = 0; mt < 4; mt++){
#pragma unroll
      for (int r2 = 0; r2 < 4; r2++){
        int m = bm + wm + (mt << 4) + ((lane >> 4) << 2) + r2;
        float v = acc[mt][nt][r2] + bia;
        if (RELU) v = fmaxf(v, 0.0f);
        if (OUTF32) ((float*)Cv)[(size_t)m * Nd + n] = v;
        else        ((u16*)Cv)[(size_t)m * Nd + n] = f2bf(v);
      }
    }
  }
}

// ---------------- bf16 MFMA GEMM (64x64), async staging, token GEMMs ----------------
template<int RELU, int OUTF32>
__global__ __launch_bounds__(256) void gemm64(const u16* __restrict__ A,
                                              const u16* __restrict__ WT,
                                              const float* __restrict__ bias,
                                              void* __restrict__ Cv,
                                              int Kd, int Nd){
  __shared__ u16 As[64][32];
  __shared__ u16 Bs[64][32];
  const int t = threadIdx.x;
  const int bm = blockIdx.y << 6;
  const int bn = blockIdx.x << 6;
  const int wave = t >> 6;
  const int lane = t & 63;
  const int wm = (wave & 1) << 5;
  const int wn = (wave >> 1) << 5;
  const int lm = lane & 15;
  const int lk = (lane >> 4) << 3;
  u16* AsF = &As[0][0];
  u16* BsF = &Bs[0][0];
  const int wbase = wave << 6;
  f32x4 acc[2][2] = {};
  for (int k0 = 0; k0 < Kd; k0 += 32){
    {
      int r = t >> 2;
      int c = (t & 3) << 3;
      int dst = wbase << 3;
      ld_g2l(A  + (size_t)(bm + r) * Kd + k0 + c, AsF + dst);
      ld_g2l(WT + (size_t)(bn + r) * Kd + k0 + c, BsF + dst);
    }
    __syncthreads();
    short8 af[2], bfr[2];
#pragma unroll
    for (int mt = 0; mt < 2; mt++) af[mt] = *(const short8*)&As[wm + (mt << 4) + lm][lk];
#pragma unroll
    for (int nt = 0; nt < 2; nt++) bfr[nt] = *(const short8*)&Bs[wn + (nt << 4) + lm][lk];
#pragma unroll
    for (int mt = 0; mt < 2; mt++)
#pragma unroll
      for (int nt = 0; nt < 2; nt++)
        acc[mt][nt] = __builtin_amdgcn_mfma_f32_16x16x32_bf16(af[mt], bfr[nt], acc[mt][nt], 0, 0, 0);
    __syncthreads();
  }
#pragma unroll
  for (int nt = 0; nt < 2; nt++){
    int n = bn + wn + (nt << 4) + lm;
    float bia = bias[n];
#pragma unroll
    for (int mt = 0; mt < 2; mt++){
#pragma unroll
      for (int r2 = 0; r2 < 4; r2++){
        int m = bm + wm + (mt << 4) + ((lane >> 4) << 2) + r2;
        float v = acc[mt][nt][r2] + bia;
        if (RELU) v = fmaxf(v, 0.0f);
        if (OUTF32) ((float*)Cv)[(size_t)m * Nd + n] = v;
        else        ((u16*)Cv)[(size_t)m * Nd + n] = f2bf(v);
      }
    }
  }
}

// ---------------- GEMM + fused max-pool (128x128), async staging ----------------
__global__ __launch_bounds__(256) void gemm_pool(const u16* __restrict__ A,
                                                 const u16* __restrict__ WT,
                                                 const float* __restrict__ bias,
                                                 u16* __restrict__ pooled,
                                                 int Kd, int Nd, int groupBase){
  __shared__ u16 As[128][32];
  __shared__ u16 Bs[128][32];
  const int t = threadIdx.x;
  const int bm = blockIdx.y << 7;
  const int bn = blockIdx.x << 7;
  const int wave = t >> 6;
  const int lane = t & 63;
  const int wm = (wave & 1) << 6;
  const int wn = (wave >> 1) << 6;
  const int lm = lane & 15;
  const int lk = (lane >> 4) << 3;
  u16* AsF = &As[0][0];
  u16* BsF = &Bs[0][0];
  const int wbase = wave << 6;
  f32x4 acc[4][4] = {};
  for (int k0 = 0; k0 < Kd; k0 += 32){
#pragma unroll
    for (int it = 0; it < 2; it++){
      int slot = t + (it << 8);
      int r = slot >> 2;
      int c = (slot & 3) << 3;
      int dst = (wbase + (it << 8)) << 3;
      ld_g2l(A  + (size_t)(bm + r) * Kd + k0 + c, AsF + dst);
      ld_g2l(WT + (size_t)(bn + r) * Kd + k0 + c, BsF + dst);
    }
    __syncthreads();
    short8 af[4], bfr[4];
#pragma unroll
    for (int mt = 0; mt < 4; mt++) af[mt] = *(const short8*)&As[wm + (mt << 4) + lm][lk];
#pragma unroll
    for (int nt = 0; nt < 4; nt++) bfr[nt] = *(const short8*)&Bs[wn + (nt << 4) + lm][lk];
#pragma unroll
    for (int mt = 0; mt < 4; mt++)
#pragma unroll
      for (int nt = 0; nt < 4; nt++)
        acc[mt][nt] = __builtin_amdgcn_mfma_f32_16x16x32_bf16(af[mt], bfr[nt], acc[mt][nt], 0, 0, 0);
    __syncthreads();
  }
  // each (mt) tile's 16 rows are exactly one pooling group
#pragma unroll
  for (int nt = 0; nt < 4; nt++){
    int n = bn + wn + (nt << 4) + lm;
    float bia = bias[n];
#pragma unroll
    for (int mt = 0; mt < 4; mt++){
      f32x4 a = acc[mt][nt];
      float v = fmaxf(fmaxf(a[0], a[1]), fmaxf(a[2], a[3]));
      v = fmaxf(v, __shfl_xor(v, 16));
      v = fmaxf(v, __shfl_xor(v, 32));
      if ((lane >> 4) == 0){
        int g = groupBase + (bm >> 4) + (wm >> 4) + mt;
        pooled[(size_t)g * Nd + n] = f2bf(v + bia);
      }
    }
  }
}

// ---------------- tier fallback (f32) ----------------
__global__ __launch_bounds__(256) void fill_diag(float* __restrict__ out, size_t out_elems){
  size_t i = (size_t)blockIdx.x * 256 + threadIdx.x;
  if (i >= out_elems) return;
  size_t maskStart = (size_t)B_ * M_ * D_ + (size_t)B_ * M_ * 4;
  out[i] = (i >= maskStart) ? 1.0f : 0.0f;
}

extern "C" void kernel_launch(void* const* d_in, const int* in_sizes, int n_in,
                              void* d_out, int out_size, void* d_ws, size_t ws_size,
                              hipStream_t stream){
  (void)in_sizes; (void)n_in;
  const float* coords   = (const float*)d_in[0];
  const float* features = (const float*)d_in[1];
  const float* W0 = (const float*)d_in[2];  const float* b0 = (const float*)d_in[3];
  const float* W1 = (const float*)d_in[4];  const float* b1 = (const float*)d_in[5];
  const float* W2 = (const float*)d_in[6];  const float* b2 = (const float*)d_in[7];
  const float* W3 = (const float*)d_in[8];  const float* b3 = (const float*)d_in[9];
  const float* Wn0 = (const float*)d_in[10]; const float* bn0 = (const float*)d_in[11];
  const float* Wn1 = (const float*)d_in[12]; const float* bn1 = (const float*)d_in[13];
  float* out = (float*)d_out;
  const size_t out_elems = (size_t)out_size;

  char* ws = (char*)d_ws;
  const size_t o_cent = 0;            // 16,384 (FPS order)
  const size_t o_cntS = 16384;        // 16,384 (time order)
  const size_t o_knn  = 32768;        // 65,536 -> 98,304
  const size_t o_Wb   = 131072;       // 4,587,520 bf16 W1t..Wn1t (transposed)
  const size_t o_pool = 4718592;      // 1,572,864 bf16 [1024,768]
  const size_t o_t1   = 6291456;      // 1,572,864
  const size_t o_keys = 7864320;      // 65,536 (8192 u64 FPS sync slots, step-indexed)
  const size_t o_chunk= 7929856;      // regA (R*1536 B) + regB (R*1024 B)
  const int ROWS = B_ * M_ * K_;      // 16384

  int R = 16384;
  while (R > 128 && o_chunk + (size_t)R * 2560 > ws_size) R >>= 1;
  if (d_ws == nullptr || o_chunk + (size_t)R * 2560 > ws_size){
    fill_diag<<<(int)((out_elems + 255) / 256), 256, 0, stream>>>(out, out_elems);
    return;
  }

  float* cent_fps    = (float*)(ws + o_cent);
  float* cent_sorted = (float*)(ws + o_cntS);
  int*   knn         = (int*)(ws + o_knn);
  u16* Wb   = (u16*)(ws + o_Wb);
  u16* W1t  = Wb;               u16* W2t  = Wb + 131072;
  u16* W3t  = Wb + 524288;      u16* Wn0t = Wb + 1114112;
  u16* Wn1t = Wb + 1703936;
  u16* pooled = (u16*)(ws + o_pool);
  u16* t1     = (u16*)(ws + o_t1);
  u64* keysbuf = (u64*)(ws + o_keys);
  u16* regA   = (u16*)(ws + o_chunk);                      // h1 [R,256] then h3 [R,768]
  u16* regB   = (u16*)(ws + o_chunk + (size_t)R * 1536);   // h2 [R,512]

  conv_all<<<560, 256, 0, stream>>>(W1, W2, W3, Wn0, Wn1, Wb);
  zero_keys<<<32, 256, 0, stream>>>(keysbuf);
  fps_multi<<<B_ * FG, 256, 0, stream>>>(coords, cent_fps, keysbuf);
  rank_scatter<<<B_, 128, 0, stream>>>(cent_fps, cent_sorted, out, out_elems);
  knn_kernel<<<B_ * M_, KNT, 0, stream>>>(coords, cent_sorted, knn);

  for (int rowBase = 0; rowBase < ROWS; rowBase += R){
    gather_l0<<<R / 32, 256, 0, stream>>>(features, knn, W0, b0, regA, rowBase);
    gemm_bf16<1,0><<<dim3(4, R / 128), 256, 0, stream>>>(regA, W1t, b1, regB, 256, 512);
    gemm_bf16<1,0><<<dim3(6, R / 128), 256, 0, stream>>>(regB, W2t, b2, regA, 512, 768);
    gemm_pool<<<dim3(6, R / 128), 256, 0, stream>>>(regA, W3t, b3, pooled, 768, 768, rowBase >> 4);
  }

  gemm64<1,0><<<dim3(12, (B_ * M_) / 64), 256, 0, stream>>>(pooled, Wn0t, bn0, t1, 768, 768);
  gemm64<0,1><<<dim3(12, (B_ * M_) / 64), 256, 0, stream>>>(t1, Wn1t, bn1, out, 768, 768);
}

// Round 2
// 554.085 us; speedup vs baseline: 1.1223x; 1.1223x over previous
//
#include <hip/hip_runtime.h>

#define B_ 8
#define N_ 16384
#define F_ 6
#define M_ 128
#define K_ 16
#define D_ 768

typedef unsigned short u16;
typedef unsigned int u32;
typedef unsigned long long u64;
typedef __attribute__((ext_vector_type(8))) short short8;
typedef __attribute__((ext_vector_type(4))) float f32x4;
typedef __attribute__((ext_vector_type(2))) float f32x2;

__device__ __forceinline__ u16 f2bf(float f){
  union { float f; u32 i; } v; v.f = f;
  u32 x = v.i;
  u32 r = x + 0x7FFFu + ((x >> 16) & 1u);
  return (u16)(r >> 16);
}

// async 16B global->LDS (dest = wave-uniform base + lane*16)
__device__ __forceinline__ void ld_g2l(const u16* g, u16* l){
  __builtin_amdgcn_global_load_lds((const __attribute__((address_space(1))) u32*)g,
                                   (__attribute__((address_space(3))) u32*)l, 16, 0, 0);
}

// packed dual-f32 ops (CDNA2+ full-rate packed fp32; bit-exact IEEE per lane)
__device__ __forceinline__ f32x2 pkadd(f32x2 a, f32x2 b){
  f32x2 d; asm("v_pk_add_f32 %0, %1, %2" : "=v"(d) : "v"(a), "v"(b)); return d;
}
__device__ __forceinline__ f32x2 pkmul(f32x2 a, f32x2 b){
  f32x2 d; asm("v_pk_mul_f32 %0, %1, %2" : "=v"(d) : "v"(a), "v"(b)); return d;
}

// ---------------- all weights f32 -> bf16 transposed [n][k], ONE kernel ----------------
__global__ __launch_bounds__(256) void conv_all(const float* __restrict__ W1,
                                                const float* __restrict__ W2,
                                                const float* __restrict__ W3,
                                                const float* __restrict__ Wn0,
                                                const float* __restrict__ Wn1,
                                                u16* __restrict__ Wb){
  __shared__ u16 tile[64][65];
  int blk = blockIdx.x;
  const float* W; u16* WT; int K, N, lb;
  if      (blk < 32)  { W = W1;  WT = Wb;           K = 256; N = 512; lb = blk; }
  else if (blk < 128) { W = W2;  WT = Wb + 131072;  K = 512; N = 768; lb = blk - 32; }
  else if (blk < 272) { W = W3;  WT = Wb + 524288;  K = 768; N = 768; lb = blk - 128; }
  else if (blk < 416) { W = Wn0; WT = Wb + 1114112; K = 768; N = 768; lb = blk - 272; }
  else                { W = Wn1; WT = Wb + 1703936; K = 768; N = 768; lb = blk - 416; }
  int tiles_n = N >> 6;
  int tk = lb / tiles_n, tn = lb % tiles_n;
  int k0 = tk << 6, n0 = tn << 6;
  int t = threadIdx.x;
#pragma unroll
  for (int q = 0; q < 16; q++){
    int idx = q * 256 + t;
    int kk = idx >> 6, nn = idx & 63;
    tile[kk][nn] = f2bf(W[(size_t)(k0 + kk) * N + n0 + nn]);
  }
  __syncthreads();
#pragma unroll
  for (int q = 0; q < 16; q++){
    int idx = q * 256 + t;
    int nn = idx >> 6, kk = idx & 63;
    WT[(size_t)(n0 + nn) * K + k0 + kk] = tile[kk][nn];
  }
}

// ---------------- FPS: 1 block/batch, xy in LDS, zw+md in VGPRs, packed-f32 math ----------------
// Exact semantics: d = ((dx*dx + dy*dy) + dz*dz) + dw*dw (contract off), md = min(md, d),
// argmax over md with first-max (lowest index) tie-break == jnp.argmax.
#define FPJ 16   // f32x2 pairs per thread: 16384 pts / (2*512)
__global__ __launch_bounds__(512, 2) void fps_block(const float* __restrict__ coords,
                                                    float* __restrict__ cent){
#pragma clang fp contract(off)
  __shared__ float sx[N_];          // 64 KB: x plane, natural point order
  __shared__ float sy[N_];          // 64 KB: y plane
  __shared__ u64 swk[2][8];
  int b = blockIdx.x;
  int t = threadIdx.x;
  int lane = t & 63, wave = t >> 6;
  const float* cb = coords + (size_t)b * N_ * 5;
  f32x2 pz[FPJ], pw[FPJ], md[FPJ];
#pragma unroll
  for (int j = 0; j < FPJ; j++){
    int p = t + (j << 9);
    size_t i0 = (size_t)(2 * p) * 5;
    float x0 = cb[i0+1], y0 = cb[i0+2], z0 = cb[i0+3], w0 = cb[i0+4];
    float x1 = cb[i0+6], y1 = cb[i0+7], z1 = cb[i0+8], w1 = cb[i0+9];
    *(f32x2*)&sx[2 * p] = (f32x2){x0, x1};
    *(f32x2*)&sy[2 * p] = (f32x2){y0, y1};
    pz[j] = (f32x2){z0, z1};
    pw[j] = (f32x2){w0, w1};
    md[j] = (f32x2){1e30f, 1e30f};
  }
  float cx = cb[1], cy = cb[2], cz = cb[3], ct = cb[4];
  if (t == 0){
    float* c0 = cent + (size_t)b * M_ * 4;
    c0[0]=cx; c0[1]=cy; c0[2]=cz; c0[3]=ct;
  }
  __syncthreads();
  for (int step = 1; step < M_; step++){
    // x - c computed as x + (-c): IEEE-identical, enables plain v_pk_add
    f32x2 ncx2 = (f32x2){-cx, -cx}, ncy2 = (f32x2){-cy, -cy};
    f32x2 ncz2 = (f32x2){-cz, -cz}, nct2 = (f32x2){-ct, -ct};
    float bv = -1.0f; int bi = 1 << 30;
#pragma unroll
    for (int j = 0; j < FPJ; j++){
      int p = t + (j << 9);
      f32x2 xv = *(const f32x2*)&sx[p << 1];
      f32x2 yv = *(const f32x2*)&sy[p << 1];
      f32x2 dx = pkadd(xv, ncx2);
      f32x2 dy = pkadd(yv, ncy2);
      f32x2 s  = pkadd(pkmul(dx, dx), pkmul(dy, dy));   // dx*dx + dy*dy (one rounding per op)
      f32x2 dz = pkadd(pz[j], ncz2);
      s = pkadd(s, pkmul(dz, dz));                      // + dz*dz
      f32x2 dw = pkadd(pw[j], nct2);
      s = pkadd(s, pkmul(dw, dw));                      // + dw*dw
      f32x2 m = md[j];
      m[0] = fminf(s[0], m[0]);
      m[1] = fminf(s[1], m[1]);
      md[j] = m;
      int i0 = p << 1;
      if (m[0] > bv){ bv = m[0]; bi = i0; }             // ascending-index first-max
      if (m[1] > bv){ bv = m[1]; bi = i0 + 1; }
    }
    // pack (value, index) into one sortable key: md >= 0 so f32 bits are order-monotone;
    // u64 max == (max value, then lowest index)
    union { float f; u32 u; } cv; cv.f = bv;
    u64 k = ((u64)cv.u << 32) | (u32)(N_ - 1 - bi);
#pragma unroll
    for (int off = 32; off > 0; off >>= 1){
      u64 ok = __shfl_down(k, off);
      if (ok > k) k = ok;
    }
    int par = step & 1;
    if (lane == 0) swk[par][wave] = k;
    __syncthreads();                                    // only barrier per step
    u64 fk = swk[par][0];
#pragma unroll
    for (int w = 1; w < 8; w++){ u64 wk = swk[par][w]; if (wk > fk) fk = wk; }
    int widx = N_ - 1 - (int)(fk & 0xffffffffu);
    size_t wb = (size_t)widx * 5;
    cx = cb[wb+1]; cy = cb[wb+2]; cz = cb[wb+3]; ct = cb[wb+4];
    if (t == 0){
      float* cr = cent + ((size_t)b * M_ + step) * 4;
      cr[0]=cx; cr[1]=cy; cr[2]=cz; cr[3]=ct;
    }
  }
}

// ---------------- stable rank by centroid time; relabel early; f32 outputs ----------------
__global__ __launch_bounds__(128) void rank_scatter(const float* __restrict__ cent_fps,
                                                    float* __restrict__ cent_sorted,
                                                    float* __restrict__ out,
                                                    size_t out_elems){
  int b = blockIdx.x, m = threadIdx.x;
  __shared__ float tt[M_];
  const float* row = cent_fps + ((size_t)b * M_ + m) * 4;
  float x=row[0], y=row[1], z=row[2], w=row[3];
  tt[m] = w;
  __syncthreads();
  int rank = 0;
  for (int j = 0; j < M_; j++){
    float tj = tt[j];
    if (tj < w || (tj == w && j < m)) rank++;       // stable argsort semantics
  }
  float* dst = cent_sorted + ((size_t)b * M_ + rank) * 4;
  dst[0]=x; dst[1]=y; dst[2]=z; dst[3]=w;
  size_t co = (size_t)B_ * M_ * D_ + ((size_t)b * M_ + rank) * 4;
  if (co + 3 < out_elems){
    out[co+0]=x; out[co+1]=y; out[co+2]=z; out[co+3]=w;
  }
  size_t mo = (size_t)B_ * M_ * D_ + (size_t)B_ * M_ * 4 + (size_t)b * M_ + m;
  if (mo < out_elems) out[mo] = 1.0f;              // mask = True -> 1.0f
}

// ---------------- kNN: f32, np op order, stable-min extraction ----------------
#define KNT 512
#define KPT 32
__global__ __launch_bounds__(512) void knn_kernel(const float* __restrict__ coords,
                                                  const float* __restrict__ cent,
                                                  int* __restrict__ knn){
#pragma clang fp contract(off)
  int cm = blockIdx.x;
  int b = cm >> 7;
  const float* cb = coords + (size_t)b * N_ * 5;
  int t = threadIdx.x;
  float cx=cent[cm*4+0], cy=cent[cm*4+1], cz=cent[cm*4+2], ct=cent[cm*4+3];
  float dist[KPT];
#pragma unroll
  for (int j = 0; j < KPT; j++){
    size_t i = t + j * KNT;
    float dx=cb[i*5+1]-cx, dy=cb[i*5+2]-cy, dz=cb[i*5+3]-cz, dw=cb[i*5+4]-ct;
    float d = ((dx*dx + dy*dy) + dz*dz) + dw*dw;
    dist[j] = sqrtf(d);                            // IEEE f32 sqrt = np.sqrt(f32)
  }
  __shared__ float s_wv[8];
  __shared__ int s_wi[8];
  __shared__ int s_bi;
  for (int r = 0; r < K_; r++){
    float bv = 3e38f; int bi = 1 << 30;
#pragma unroll
    for (int j = 0; j < KPT; j++){
      int i = t + j * KNT;
      float v = dist[j];
      if (v < bv){ bv = v; bi = i; }               // first-min kept
    }
#pragma unroll
    for (int off = 32; off > 0; off >>= 1){
      float ov = __shfl_down(bv, off);
      int oi = __shfl_down(bi, off);
      if (ov < bv || (ov == bv && oi < bi)){ bv = ov; bi = oi; }
    }
    if ((t & 63) == 0){ s_wv[t >> 6] = bv; s_wi[t >> 6] = bi; }
    __syncthreads();
    if (t == 0){
      float fv = s_wv[0]; int fi = s_wi[0];
      for (int w = 1; w < 8; w++){
        float wv = s_wv[w]; int wi = s_wi[w];
        if (wv < fv || (wv == fv && wi < fi)){ fv = wv; fi = wi; }
      }
      s_bi = fi;
      knn[(size_t)cm * K_ + r] = fi & (N_ - 1);
    }
    __syncthreads();
    int wi = s_bi;
#pragma unroll
    for (int j = 0; j < KPT; j++){
      if (t + j * KNT == wi) dist[j] = 3e38f;
    }
  }
}

// ---------------- gather + layer0: 32 rows/block, W0/b0/features LDS-staged ----------------
__global__ __launch_bounds__(256) void gather_l0(const float* __restrict__ feat,
                                                 const int* __restrict__ knn,
                                                 const float* __restrict__ W0,
                                                 const float* __restrict__ b0,
                                                 u16* __restrict__ h1,
                                                 int rowBase){
  __shared__ float sW[F_][256];
  __shared__ float sb[256];
  __shared__ float sfa[32][F_];
  int t = threadIdx.x;
#pragma unroll
  for (int k = 0; k < F_; k++) sW[k][t] = W0[k * 256 + t];
  sb[t] = b0[t];
  if (t < 32 * F_){
    int r = t / F_, k = t % F_;
    int grow = rowBase + blockIdx.x * 32 + r;
    int bb = grow >> 11;                          // /(M*K)=2048
    int idx = knn[grow] & (N_ - 1);
    sfa[r][k] = feat[((size_t)bb * N_ + idx) * F_ + k];
  }
  __syncthreads();
#pragma unroll 4
  for (int r = 0; r < 32; r++){
    float acc = sb[t];
#pragma unroll
    for (int k = 0; k < F_; k++) acc = fmaf(sfa[r][k], sW[k][t], acc);
    int lrow = blockIdx.x * 32 + r;
    h1[(size_t)lrow * 256 + t] = f2bf(fmaxf(acc, 0.0f));
  }
}

// ---------------- bf16 MFMA GEMM (128x128), async global->LDS staging ----------------
// Unpadded [128][32] rows (64B): dest = wave-uniform base + lane*16 (m97 layout).
template<int RELU, int OUTF32>
__global__ __launch_bounds__(256) void gemm_bf16(const u16* __restrict__ A,
                                                 const u16* __restrict__ WT,
                                                 const float* __restrict__ bias,
                                                 void* __restrict__ Cv,
                                                 int Kd, int Nd){
  __shared__ u16 As[128][32];
  __shared__ u16 Bs[128][32];
  const int t = threadIdx.x;
  const int bm = blockIdx.y << 7;
  const int bn = blockIdx.x << 7;
  const int wave = t >> 6;
  const int lane = t & 63;
  const int wm = (wave & 1) << 6;
  const int wn = (wave >> 1) << 6;
  const int lm = lane & 15;
  const int lk = (lane >> 4) << 3;
  u16* AsF = &As[0][0];
  u16* BsF = &Bs[0][0];
  const int wbase = wave << 6;               // t - lane
  f32x4 acc[4][4] = {};
  for (int k0 = 0; k0 < Kd; k0 += 32){
#pragma unroll
    for (int it = 0; it < 2; it++){
      int slot = t + (it << 8);
      int r = slot >> 2;
      int c = (slot & 3) << 3;
      int dst = (wbase + (it << 8)) << 3;    // u16 elements; +lane*16B by HW
      ld_g2l(A  + (size_t)(bm + r) * Kd + k0 + c, AsF + dst);
      ld_g2l(WT + (size_t)(bn + r) * Kd + k0 + c, BsF + dst);
    }
    __syncthreads();
    short8 af[4], bfr[4];
#pragma unroll
    for (int mt = 0; mt < 4; mt++) af[mt] = *(const short8*)&As[wm + (mt << 4) + lm][lk];
#pragma unroll
    for (int nt = 0; nt < 4; nt++) bfr[nt] = *(const short8*)&Bs[wn + (nt << 4) + lm][lk];
#pragma unroll
    for (int mt = 0; mt < 4; mt++)
#pragma unroll
      for (int nt = 0; nt < 4; nt++)
        acc[mt][nt] = __builtin_amdgcn_mfma_f32_16x16x32_bf16(af[mt], bfr[nt], acc[mt][nt], 0, 0, 0);
    __syncthreads();
  }
#pragma unroll
  for (int nt = 0; nt < 4; nt++){
    int n = bn + wn + (nt << 4) + lm;
    float bia = bias[n];
#pragma unroll
    for (int mt = 0; mt < 4; mt++){
#pragma unroll
      for (int r2 = 0; r2 < 4; r2++){
        int m = bm + wm + (mt << 4) + ((lane >> 4) << 2) + r2;
        float v = acc[mt][nt][r2] + bia;
        if (RELU) v = fmaxf(v, 0.0f);
        if (OUTF32) ((float*)Cv)[(size_t)m * Nd + n] = v;
        else        ((u16*)Cv)[(size_t)m * Nd + n] = f2bf(v);
      }
    }
  }
}

// ---------------- bf16 MFMA GEMM (64x64), async staging, token GEMMs ----------------
template<int RELU, int OUTF32>
__global__ __launch_bounds__(256) void gemm64(const u16* __restrict__ A,
                                              const u16* __restrict__ WT,
                                              const float* __restrict__ bias,
                                              void* __restrict__ Cv,
                                              int Kd, int Nd){
  __shared__ u16 As[64][32];
  __shared__ u16 Bs[64][32];
  const int t = threadIdx.x;
  const int bm = blockIdx.y << 6;
  const int bn = blockIdx.x << 6;
  const int wave = t >> 6;
  const int lane = t & 63;
  const int wm = (wave & 1) << 5;
  const int wn = (wave >> 1) << 5;
  const int lm = lane & 15;
  const int lk = (lane >> 4) << 3;
  u16* AsF = &As[0][0];
  u16* BsF = &Bs[0][0];
  const int wbase = wave << 6;
  f32x4 acc[2][2] = {};
  for (int k0 = 0; k0 < Kd; k0 += 32){
    {
      int r = t >> 2;
      int c = (t & 3) << 3;
      int dst = wbase << 3;
      ld_g2l(A  + (size_t)(bm + r) * Kd + k0 + c, AsF + dst);
      ld_g2l(WT + (size_t)(bn + r) * Kd + k0 + c, BsF + dst);
    }
    __syncthreads();
    short8 af[2], bfr[2];
#pragma unroll
    for (int mt = 0; mt < 2; mt++) af[mt] = *(const short8*)&As[wm + (mt << 4) + lm][lk];
#pragma unroll
    for (int nt = 0; nt < 2; nt++) bfr[nt] = *(const short8*)&Bs[wn + (nt << 4) + lm][lk];
#pragma unroll
    for (int mt = 0; mt < 2; mt++)
#pragma unroll
      for (int nt = 0; nt < 2; nt++)
        acc[mt][nt] = __builtin_amdgcn_mfma_f32_16x16x32_bf16(af[mt], bfr[nt], acc[mt][nt], 0, 0, 0);
    __syncthreads();
  }
#pragma unroll
  for (int nt = 0; nt < 2; nt++){
    int n = bn + wn + (nt << 4) + lm;
    float bia = bias[n];
#pragma unroll
    for (int mt = 0; mt < 2; mt++){
#pragma unroll
      for (int r2 = 0; r2 < 4; r2++){
        int m = bm + wm + (mt << 4) + ((lane >> 4) << 2) + r2;
        float v = acc[mt][nt][r2] + bia;
        if (RELU) v = fmaxf(v, 0.0f);
        if (OUTF32) ((float*)Cv)[(size_t)m * Nd + n] = v;
        else        ((u16*)Cv)[(size_t)m * Nd + n] = f2bf(v);
      }
    }
  }
}

// ---------------- GEMM + fused max-pool (128x128), async staging ----------------
__global__ __launch_bounds__(256) void gemm_pool(const u16* __restrict__ A,
                                                 const u16* __restrict__ WT,
                                                 const float* __restrict__ bias,
                                                 u16* __restrict__ pooled,
                                                 int Kd, int Nd, int groupBase){
  __shared__ u16 As[128][32];
  __shared__ u16 Bs[128][32];
  const int t = threadIdx.x;
  const int bm = blockIdx.y << 7;
  const int bn = blockIdx.x << 7;
  const int wave = t >> 6;
  const int lane = t & 63;
  const int wm = (wave & 1) << 6;
  const int wn = (wave >> 1) << 6;
  const int lm = lane & 15;
  const int lk = (lane >> 4) << 3;
  u16* AsF = &As[0][0];
  u16* BsF = &Bs[0][0];
  const int wbase = wave << 6;
  f32x4 acc[4][4] = {};
  for (int k0 = 0; k0 < Kd; k0 += 32){
#pragma unroll
    for (int it = 0; it < 2; it++){
      int slot = t + (it << 8);
      int r = slot >> 2;
      int c = (slot & 3) << 3;
      int dst = (wbase + (it << 8)) << 3;
      ld_g2l(A  + (size_t)(bm + r) * Kd + k0 + c, AsF + dst);
      ld_g2l(WT + (size_t)(bn + r) * Kd + k0 + c, BsF + dst);
    }
    __syncthreads();
    short8 af[4], bfr[4];
#pragma unroll
    for (int mt = 0; mt < 4; mt++) af[mt] = *(const short8*)&As[wm + (mt << 4) + lm][lk];
#pragma unroll
    for (int nt = 0; nt < 4; nt++) bfr[nt] = *(const short8*)&Bs[wn + (nt << 4) + lm][lk];
#pragma unroll
    for (int mt = 0; mt < 4; mt++)
#pragma unroll
      for (int nt = 0; nt < 4; nt++)
        acc[mt][nt] = __builtin_amdgcn_mfma_f32_16x16x32_bf16(af[mt], bfr[nt], acc[mt][nt], 0, 0, 0);
    __syncthreads();
  }
  // each (mt) tile's 16 rows are exactly one pooling group
#pragma unroll
  for (int nt = 0; nt < 4; nt++){
    int n = bn + wn + (nt << 4) + lm;
    float bia = bias[n];
#pragma unroll
    for (int mt = 0; mt < 4; mt++){
      f32x4 a = acc[mt][nt];
      float v = fmaxf(fmaxf(a[0], a[1]), fmaxf(a[2], a[3]));
      v = fmaxf(v, __shfl_xor(v, 16));
      v = fmaxf(v, __shfl_xor(v, 32));
      if ((lane >> 4) == 0){
        int g = groupBase + (bm >> 4) + (wm >> 4) + mt;
        pooled[(size_t)g * Nd + n] = f2bf(v + bia);
      }
    }
  }
}

// ---------------- tier fallback (f32) ----------------
__global__ __launch_bounds__(256) void fill_diag(float* __restrict__ out, size_t out_elems){
  size_t i = (size_t)blockIdx.x * 256 + threadIdx.x;
  if (i >= out_elems) return;
  size_t maskStart = (size_t)B_ * M_ * D_ + (size_t)B_ * M_ * 4;
  out[i] = (i >= maskStart) ? 1.0f : 0.0f;
}

extern "C" void kernel_launch(void* const* d_in, const int* in_sizes, int n_in,
                              void* d_out, int out_size, void* d_ws, size_t ws_size,
                              hipStream_t stream){
  (void)in_sizes; (void)n_in;
  const float* coords   = (const float*)d_in[0];
  const float* features = (const float*)d_in[1];
  const float* W0 = (const float*)d_in[2];  const float* b0 = (const float*)d_in[3];
  const float* W1 = (const float*)d_in[4];  const float* b1 = (const float*)d_in[5];
  const float* W2 = (const float*)d_in[6];  const float* b2 = (const float*)d_in[7];
  const float* W3 = (const float*)d_in[8];  const float* b3 = (const float*)d_in[9];
  const float* Wn0 = (const float*)d_in[10]; const float* bn0 = (const float*)d_in[11];
  const float* Wn1 = (const float*)d_in[12]; const float* bn1 = (const float*)d_in[13];
  float* out = (float*)d_out;
  const size_t out_elems = (size_t)out_size;

  char* ws = (char*)d_ws;
  const size_t o_cent = 0;            // 16,384 (FPS order)
  const size_t o_cntS = 16384;        // 16,384 (time order)
  const size_t o_knn  = 32768;        // 65,536 -> 98,304
  const size_t o_Wb   = 131072;       // 4,587,520 bf16 W1t..Wn1t (transposed)
  const size_t o_pool = 4718592;      // 1,572,864 bf16 [1024,768]
  const size_t o_t1   = 6291456;      // 1,572,864
  const size_t o_chunk= 7864320;      // regA (R*1536 B) + regB (R*1024 B)
  const int ROWS = B_ * M_ * K_;      // 16384

  int R = 16384;
  while (R > 128 && o_chunk + (size_t)R * 2560 > ws_size) R >>= 1;
  if (d_ws == nullptr || o_chunk + (size_t)R * 2560 > ws_size){
    fill_diag<<<(int)((out_elems + 255) / 256), 256, 0, stream>>>(out, out_elems);
    return;
  }

  float* cent_fps    = (float*)(ws + o_cent);
  float* cent_sorted = (float*)(ws + o_cntS);
  int*   knn         = (int*)(ws + o_knn);
  u16* Wb   = (u16*)(ws + o_Wb);
  u16* W1t  = Wb;               u16* W2t  = Wb + 131072;
  u16* W3t  = Wb + 524288;      u16* Wn0t = Wb + 1114112;
  u16* Wn1t = Wb + 1703936;
  u16* pooled = (u16*)(ws + o_pool);
  u16* t1     = (u16*)(ws + o_t1);
  u16* regA   = (u16*)(ws + o_chunk);                      // h1 [R,256] then h3 [R,768]
  u16* regB   = (u16*)(ws + o_chunk + (size_t)R * 1536);   // h2 [R,512]

  conv_all<<<560, 256, 0, stream>>>(W1, W2, W3, Wn0, Wn1, Wb);
  fps_block<<<B_, 512, 0, stream>>>(coords, cent_fps);
  rank_scatter<<<B_, 128, 0, stream>>>(cent_fps, cent_sorted, out, out_elems);
  knn_kernel<<<B_ * M_, KNT, 0, stream>>>(coords, cent_sorted, knn);

  for (int rowBase = 0; rowBase < ROWS; rowBase += R){
    gather_l0<<<R / 32, 256, 0, stream>>>(features, knn, W0, b0, regA, rowBase);
    gemm_bf16<1,0><<<dim3(4, R / 128), 256, 0, stream>>>(regA, W1t, b1, regB, 256, 512);
    gemm_bf16<1,0><<<dim3(6, R / 128), 256, 0, stream>>>(regB, W2t, b2, regA, 512, 768);
    gemm_pool<<<dim3(6, R / 128), 256, 0, stream>>>(regA, W3t, b3, pooled, 768, 768, rowBase >> 4);
  }

  gemm64<1,0><<<dim3(12, (B_ * M_) / 64), 256, 0, stream>>>(pooled, Wn0t, bn0, t1, 768, 768);
  gemm64<0,1><<<dim3(12, (B_ * M_) / 64), 256, 0, stream>>>(t1, Wn1t, bn1, out, 768, 768);
}

// Round 3
// 551.991 us; speedup vs baseline: 1.1266x; 1.0038x over previous
//
#include <hip/hip_runtime.h>

#define B_ 8
#define N_ 16384
#define F_ 6
#define M_ 128
#define K_ 16
#define D_ 768

typedef unsigned short u16;
typedef unsigned int u32;
typedef unsigned long long u64;
typedef __attribute__((ext_vector_type(8))) short short8;
typedef __attribute__((ext_vector_type(4))) float f32x4;
typedef __attribute__((ext_vector_type(2))) float f32x2;

__device__ __forceinline__ u16 f2bf(float f){
  union { float f; u32 i; } v; v.f = f;
  u32 x = v.i;
  u32 r = x + 0x7FFFu + ((x >> 16) & 1u);
  return (u16)(r >> 16);
}

// async 16B global->LDS (dest = wave-uniform base + lane*16)
__device__ __forceinline__ void ld_g2l(const u16* g, u16* l){
  __builtin_amdgcn_global_load_lds((const __attribute__((address_space(1))) u32*)g,
                                   (__attribute__((address_space(3))) u32*)l, 16, 0, 0);
}

// packed dual-f32 ops (CDNA2+ full-rate packed fp32; bit-exact IEEE per lane)
__device__ __forceinline__ f32x2 pkadd(f32x2 a, f32x2 b){
  f32x2 d; asm("v_pk_add_f32 %0, %1, %2" : "=v"(d) : "v"(a), "v"(b)); return d;
}
__device__ __forceinline__ f32x2 pkmul(f32x2 a, f32x2 b){
  f32x2 d; asm("v_pk_mul_f32 %0, %1, %2" : "=v"(d) : "v"(a), "v"(b)); return d;
}

// ---------------- all weights f32 -> bf16 transposed [n][k], ONE kernel ----------------
__global__ __launch_bounds__(256) void conv_all(const float* __restrict__ W1,
                                                const float* __restrict__ W2,
                                                const float* __restrict__ W3,
                                                const float* __restrict__ Wn0,
                                                const float* __restrict__ Wn1,
                                                u16* __restrict__ Wb){
  __shared__ u16 tile[64][65];
  int blk = blockIdx.x;
  const float* W; u16* WT; int K, N, lb;
  if      (blk < 32)  { W = W1;  WT = Wb;           K = 256; N = 512; lb = blk; }
  else if (blk < 128) { W = W2;  WT = Wb + 131072;  K = 512; N = 768; lb = blk - 32; }
  else if (blk < 272) { W = W3;  WT = Wb + 524288;  K = 768; N = 768; lb = blk - 128; }
  else if (blk < 416) { W = Wn0; WT = Wb + 1114112; K = 768; N = 768; lb = blk - 272; }
  else                { W = Wn1; WT = Wb + 1703936; K = 768; N = 768; lb = blk - 416; }
  int tiles_n = N >> 6;
  int tk = lb / tiles_n, tn = lb % tiles_n;
  int k0 = tk << 6, n0 = tn << 6;
  int t = threadIdx.x;
#pragma unroll
  for (int q = 0; q < 16; q++){
    int idx = q * 256 + t;
    int kk = idx >> 6, nn = idx & 63;
    tile[kk][nn] = f2bf(W[(size_t)(k0 + kk) * N + n0 + nn]);
  }
  __syncthreads();
#pragma unroll
  for (int q = 0; q < 16; q++){
    int idx = q * 256 + t;
    int nn = idx >> 6, kk = idx & 63;
    WT[(size_t)(n0 + nn) * K + k0 + kk] = tile[kk][nn];
  }
}

// ---------------- FPS: 1 block/batch, 1024 thr, ALL state in registers (80 VGPR) ----------------
// Exact semantics: d = ((dx*dx + dy*dy) + dz*dz) + dw*dw (contract off), md = min(md, d),
// argmax over md with first-max (lowest index) tie-break == jnp.argmax.
// asm "+v" guard forbids rematerialization of the coordinate registers (the round-0/2
// hidden cost: compiler re-loaded loop-invariant coords from L2 every step).
#define FPJ 8   // f32x2 pairs per thread: 16384 pts / (2*1024)
__global__ __launch_bounds__(1024, 4) void fps_block(const float* __restrict__ coords,
                                                     float* __restrict__ cent){
#pragma clang fp contract(off)
  __shared__ u64 swk[2][16];
  int b = blockIdx.x;
  int t = threadIdx.x;
  int lane = t & 63, wave = t >> 6;
  const float* cb = coords + (size_t)b * N_ * 5;
  f32x2 px[FPJ], py[FPJ], pz[FPJ], pw[FPJ], md[FPJ];
#pragma unroll
  for (int j = 0; j < FPJ; j++){
    int p = t + (j << 10);
    size_t i0 = (size_t)(2 * p) * 5;
    px[j] = (f32x2){cb[i0+1], cb[i0+6]};
    py[j] = (f32x2){cb[i0+2], cb[i0+7]};
    pz[j] = (f32x2){cb[i0+3], cb[i0+8]};
    pw[j] = (f32x2){cb[i0+4], cb[i0+9]};
    md[j] = (f32x2){1e30f, 1e30f};
    asm volatile("" : "+v"(px[j]), "+v"(py[j]), "+v"(pz[j]), "+v"(pw[j]));
  }
  float cx = cb[1], cy = cb[2], cz = cb[3], ct = cb[4];
  if (t == 0){
    float* c0 = cent + (size_t)b * M_ * 4;
    c0[0]=cx; c0[1]=cy; c0[2]=cz; c0[3]=ct;
  }
  for (int step = 1; step < M_; step++){
    // x - c computed as x + (-c): IEEE-identical, enables plain v_pk_add
    f32x2 ncx2 = (f32x2){-cx, -cx}, ncy2 = (f32x2){-cy, -cy};
    f32x2 ncz2 = (f32x2){-cz, -cz}, nct2 = (f32x2){-ct, -ct};
    float bv = -1.0f; int bi = 1 << 30;
#pragma unroll
    for (int j = 0; j < FPJ; j++){
      f32x2 dx = pkadd(px[j], ncx2);
      f32x2 dy = pkadd(py[j], ncy2);
      f32x2 s  = pkadd(pkmul(dx, dx), pkmul(dy, dy));   // dx*dx + dy*dy (one rounding per op)
      f32x2 dz = pkadd(pz[j], ncz2);
      s = pkadd(s, pkmul(dz, dz));                      // + dz*dz
      f32x2 dw = pkadd(pw[j], nct2);
      s = pkadd(s, pkmul(dw, dw));                      // + dw*dw
      f32x2 m = md[j];
      m[0] = fminf(s[0], m[0]);
      m[1] = fminf(s[1], m[1]);
      md[j] = m;
      int i0 = (t + (j << 10)) << 1;
      if (m[0] > bv){ bv = m[0]; bi = i0; }             // ascending-index first-max
      if (m[1] > bv){ bv = m[1]; bi = i0 + 1; }
    }
    // pack (value, index) into one sortable key: md >= 0 so f32 bits are order-monotone;
    // u64 max == (max value, then lowest index)
    union { float f; u32 u; } cv; cv.f = bv;
    u64 k = ((u64)cv.u << 32) | (u32)(N_ - 1 - bi);
#pragma unroll
    for (int off = 32; off > 0; off >>= 1){
      u64 ok = __shfl_down(k, off);
      if (ok > k) k = ok;
    }
    int par = step & 1;
    if (lane == 0) swk[par][wave] = k;
    __syncthreads();                                    // only barrier per step
    u64 fk = swk[par][0];
#pragma unroll
    for (int w = 1; w < 16; w++){ u64 wk = swk[par][w]; if (wk > fk) fk = wk; }
    int widx = N_ - 1 - (int)(fk & 0xffffffffu);
    size_t wb = (size_t)widx * 5;
    cx = cb[wb+1]; cy = cb[wb+2]; cz = cb[wb+3]; ct = cb[wb+4];
    if (t == 0){
      float* cr = cent + ((size_t)b * M_ + step) * 4;
      cr[0]=cx; cr[1]=cy; cr[2]=cz; cr[3]=ct;
    }
  }
}

// ---------------- stable rank by centroid time; relabel early; f32 outputs ----------------
__global__ __launch_bounds__(128) void rank_scatter(const float* __restrict__ cent_fps,
                                                    float* __restrict__ cent_sorted,
                                                    float* __restrict__ out,
                                                    size_t out_elems){
  int b = blockIdx.x, m = threadIdx.x;
  __shared__ float tt[M_];
  const float* row = cent_fps + ((size_t)b * M_ + m) * 4;
  float x=row[0], y=row[1], z=row[2], w=row[3];
  tt[m] = w;
  __syncthreads();
  int rank = 0;
  for (int j = 0; j < M_; j++){
    float tj = tt[j];
    if (tj < w || (tj == w && j < m)) rank++;       // stable argsort semantics
  }
  float* dst = cent_sorted + ((size_t)b * M_ + rank) * 4;
  dst[0]=x; dst[1]=y; dst[2]=z; dst[3]=w;
  size_t co = (size_t)B_ * M_ * D_ + ((size_t)b * M_ + rank) * 4;
  if (co + 3 < out_elems){
    out[co+0]=x; out[co+1]=y; out[co+2]=z; out[co+3]=w;
  }
  size_t mo = (size_t)B_ * M_ * D_ + (size_t)B_ * M_ * 4 + (size_t)b * M_ + m;
  if (mo < out_elems) out[mo] = 1.0f;              // mask = True -> 1.0f
}

// ---------------- kNN: f32, np op order, stable-min extraction ----------------
#define KNT 512
#define KPT 32
__global__ __launch_bounds__(512) void knn_kernel(const float* __restrict__ coords,
                                                  const float* __restrict__ cent,
                                                  int* __restrict__ knn){
#pragma clang fp contract(off)
  int cm = blockIdx.x;
  int b = cm >> 7;
  const float* cb = coords + (size_t)b * N_ * 5;
  int t = threadIdx.x;
  float cx=cent[cm*4+0], cy=cent[cm*4+1], cz=cent[cm*4+2], ct=cent[cm*4+3];
  float dist[KPT];
#pragma unroll
  for (int j = 0; j < KPT; j++){
    size_t i = t + j * KNT;
    float dx=cb[i*5+1]-cx, dy=cb[i*5+2]-cy, dz=cb[i*5+3]-cz, dw=cb[i*5+4]-ct;
    float d = ((dx*dx + dy*dy) + dz*dz) + dw*dw;
    dist[j] = sqrtf(d);                            // IEEE f32 sqrt = np.sqrt(f32)
  }
  __shared__ float s_wv[8];
  __shared__ int s_wi[8];
  __shared__ int s_bi;
  for (int r = 0; r < K_; r++){
    float bv = 3e38f; int bi = 1 << 30;
#pragma unroll
    for (int j = 0; j < KPT; j++){
      int i = t + j * KNT;
      float v = dist[j];
      if (v < bv){ bv = v; bi = i; }               // first-min kept
    }
#pragma unroll
    for (int off = 32; off > 0; off >>= 1){
      float ov = __shfl_down(bv, off);
      int oi = __shfl_down(bi, off);
      if (ov < bv || (ov == bv && oi < bi)){ bv = ov; bi = oi; }
    }
    if ((t & 63) == 0){ s_wv[t >> 6] = bv; s_wi[t >> 6] = bi; }
    __syncthreads();
    if (t == 0){
      float fv = s_wv[0]; int fi = s_wi[0];
      for (int w = 1; w < 8; w++){
        float wv = s_wv[w]; int wi = s_wi[w];
        if (wv < fv || (wv == fv && wi < fi)){ fv = wv; fi = wi; }
      }
      s_bi = fi;
      knn[(size_t)cm * K_ + r] = fi & (N_ - 1);
    }
    __syncthreads();
    int wi = s_bi;
#pragma unroll
    for (int j = 0; j < KPT; j++){
      if (t + j * KNT == wi) dist[j] = 3e38f;
    }
  }
}

// ---------------- gather + layer0: 32 rows/block, W0/b0/features LDS-staged ----------------
__global__ __launch_bounds__(256) void gather_l0(const float* __restrict__ feat,
                                                 const int* __restrict__ knn,
                                                 const float* __restrict__ W0,
                                                 const float* __restrict__ b0,
                                                 u16* __restrict__ h1,
                                                 int rowBase){
  __shared__ float sW[F_][256];
  __shared__ float sb[256];
  __shared__ float sfa[32][F_];
  int t = threadIdx.x;
#pragma unroll
  for (int k = 0; k < F_; k++) sW[k][t] = W0[k * 256 + t];
  sb[t] = b0[t];
  if (t < 32 * F_){
    int r = t / F_, k = t % F_;
    int grow = rowBase + blockIdx.x * 32 + r;
    int bb = grow >> 11;                          // /(M*K)=2048
    int idx = knn[grow] & (N_ - 1);
    sfa[r][k] = feat[((size_t)bb * N_ + idx) * F_ + k];
  }
  __syncthreads();
#pragma unroll 4
  for (int r = 0; r < 32; r++){
    float acc = sb[t];
#pragma unroll
    for (int k = 0; k < F_; k++) acc = fmaf(sfa[r][k], sW[k][t], acc);
    int lrow = blockIdx.x * 32 + r;
    h1[(size_t)lrow * 256 + t] = f2bf(fmaxf(acc, 0.0f));
  }
}

// ---------------- bf16 MFMA GEMM (128x128), async global->LDS staging ----------------
// Unpadded [128][32] rows (64B): dest = wave-uniform base + lane*16 (m97 layout).
template<int RELU, int OUTF32>
__global__ __launch_bounds__(256) void gemm_bf16(const u16* __restrict__ A,
                                                 const u16* __restrict__ WT,
                                                 const float* __restrict__ bias,
                                                 void* __restrict__ Cv,
                                                 int Kd, int Nd){
  __shared__ u16 As[128][32];
  __shared__ u16 Bs[128][32];
  const int t = threadIdx.x;
  const int bm = blockIdx.y << 7;
  const int bn = blockIdx.x << 7;
  const int wave = t >> 6;
  const int lane = t & 63;
  const int wm = (wave & 1) << 6;
  const int wn = (wave >> 1) << 6;
  const int lm = lane & 15;
  const int lk = (lane >> 4) << 3;
  u16* AsF = &As[0][0];
  u16* BsF = &Bs[0][0];
  const int wbase = wave << 6;               // t - lane
  f32x4 acc[4][4] = {};
  for (int k0 = 0; k0 < Kd; k0 += 32){
#pragma unroll
    for (int it = 0; it < 2; it++){
      int slot = t + (it << 8);
      int r = slot >> 2;
      int c = (slot & 3) << 3;
      int dst = (wbase + (it << 8)) << 3;    // u16 elements; +lane*16B by HW
      ld_g2l(A  + (size_t)(bm + r) * Kd + k0 + c, AsF + dst);
      ld_g2l(WT + (size_t)(bn + r) * Kd + k0 + c, BsF + dst);
    }
    __syncthreads();
    short8 af[4], bfr[4];
#pragma unroll
    for (int mt = 0; mt < 4; mt++) af[mt] = *(const short8*)&As[wm + (mt << 4) + lm][lk];
#pragma unroll
    for (int nt = 0; nt < 4; nt++) bfr[nt] = *(const short8*)&Bs[wn + (nt << 4) + lm][lk];
#pragma unroll
    for (int mt = 0; mt < 4; mt++)
#pragma unroll
      for (int nt = 0; nt < 4; nt++)
        acc[mt][nt] = __builtin_amdgcn_mfma_f32_16x16x32_bf16(af[mt], bfr[nt], acc[mt][nt], 0, 0, 0);
    __syncthreads();
  }
#pragma unroll
  for (int nt = 0; nt < 4; nt++){
    int n = bn + wn + (nt << 4) + lm;
    float bia = bias[n];
#pragma unroll
    for (int mt = 0; mt < 4; mt++){
#pragma unroll
      for (int r2 = 0; r2 < 4; r2++){
        int m = bm + wm + (mt << 4) + ((lane >> 4) << 2) + r2;
        float v = acc[mt][nt][r2] + bia;
        if (RELU) v = fmaxf(v, 0.0f);
        if (OUTF32) ((float*)Cv)[(size_t)m * Nd + n] = v;
        else        ((u16*)Cv)[(size_t)m * Nd + n] = f2bf(v);
      }
    }
  }
}

// ---------------- bf16 MFMA GEMM (64x64), async staging, token GEMMs ----------------
template<int RELU, int OUTF32>
__global__ __launch_bounds__(256) void gemm64(const u16* __restrict__ A,
                                              const u16* __restrict__ WT,
                                              const float* __restrict__ bias,
                                              void* __restrict__ Cv,
                                              int Kd, int Nd){
  __shared__ u16 As[64][32];
  __shared__ u16 Bs[64][32];
  const int t = threadIdx.x;
  const int bm = blockIdx.y << 6;
  const int bn = blockIdx.x << 6;
  const int wave = t >> 6;
  const int lane = t & 63;
  const int wm = (wave & 1) << 5;
  const int wn = (wave >> 1) << 5;
  const int lm = lane & 15;
  const int lk = (lane >> 4) << 3;
  u16* AsF = &As[0][0];
  u16* BsF = &Bs[0][0];
  const int wbase = wave << 6;
  f32x4 acc[2][2] = {};
  for (int k0 = 0; k0 < Kd; k0 += 32){
    {
      int r = t >> 2;
      int c = (t & 3) << 3;
      int dst = wbase << 3;
      ld_g2l(A  + (size_t)(bm + r) * Kd + k0 + c, AsF + dst);
      ld_g2l(WT + (size_t)(bn + r) * Kd + k0 + c, BsF + dst);
    }
    __syncthreads();
    short8 af[2], bfr[2];
#pragma unroll
    for (int mt = 0; mt < 2; mt++) af[mt] = *(const short8*)&As[wm + (mt << 4) + lm][lk];
#pragma unroll
    for (int nt = 0; nt < 2; nt++) bfr[nt] = *(const short8*)&Bs[wn + (nt << 4) + lm][lk];
#pragma unroll
    for (int mt = 0; mt < 2; mt++)
#pragma unroll
      for (int nt = 0; nt < 2; nt++)
        acc[mt][nt] = __builtin_amdgcn_mfma_f32_16x16x32_bf16(af[mt], bfr[nt], acc[mt][nt], 0, 0, 0);
    __syncthreads();
  }
#pragma unroll
  for (int nt = 0; nt < 2; nt++){
    int n = bn + wn + (nt << 4) + lm;
    float bia = bias[n];
#pragma unroll
    for (int mt = 0; mt < 2; mt++){
#pragma unroll
      for (int r2 = 0; r2 < 4; r2++){
        int m = bm + wm + (mt << 4) + ((lane >> 4) << 2) + r2;
        float v = acc[mt][nt][r2] + bia;
        if (RELU) v = fmaxf(v, 0.0f);
        if (OUTF32) ((float*)Cv)[(size_t)m * Nd + n] = v;
        else        ((u16*)Cv)[(size_t)m * Nd + n] = f2bf(v);
      }
    }
  }
}

// ---------------- GEMM + fused max-pool (128x128), async staging ----------------
__global__ __launch_bounds__(256) void gemm_pool(const u16* __restrict__ A,
                                                 const u16* __restrict__ WT,
                                                 const float* __restrict__ bias,
                                                 u16* __restrict__ pooled,
                                                 int Kd, int Nd, int groupBase){
  __shared__ u16 As[128][32];
  __shared__ u16 Bs[128][32];
  const int t = threadIdx.x;
  const int bm = blockIdx.y << 7;
  const int bn = blockIdx.x << 7;
  const int wave = t >> 6;
  const int lane = t & 63;
  const int wm = (wave & 1) << 6;
  const int wn = (wave >> 1) << 6;
  const int lm = lane & 15;
  const int lk = (lane >> 4) << 3;
  u16* AsF = &As[0][0];
  u16* BsF = &Bs[0][0];
  const int wbase = wave << 6;
  f32x4 acc[4][4] = {};
  for (int k0 = 0; k0 < Kd; k0 += 32){
#pragma unroll
    for (int it = 0; it < 2; it++){
      int slot = t + (it << 8);
      int r = slot >> 2;
      int c = (slot & 3) << 3;
      int dst = (wbase + (it << 8)) << 3;
      ld_g2l(A  + (size_t)(bm + r) * Kd + k0 + c, AsF + dst);
      ld_g2l(WT + (size_t)(bn + r) * Kd + k0 + c, BsF + dst);
    }
    __syncthreads();
    short8 af[4], bfr[4];
#pragma unroll
    for (int mt = 0; mt < 4; mt++) af[mt] = *(const short8*)&As[wm + (mt << 4) + lm][lk];
#pragma unroll
    for (int nt = 0; nt < 4; nt++) bfr[nt] = *(const short8*)&Bs[wn + (nt << 4) + lm][lk];
#pragma unroll
    for (int mt = 0; mt < 4; mt++)
#pragma unroll
      for (int nt = 0; nt < 4; nt++)
        acc[mt][nt] = __builtin_amdgcn_mfma_f32_16x16x32_bf16(af[mt], bfr[nt], acc[mt][nt], 0, 0, 0);
    __syncthreads();
  }
  // each (mt) tile's 16 rows are exactly one pooling group
#pragma unroll
  for (int nt = 0; nt < 4; nt++){
    int n = bn + wn + (nt << 4) + lm;
    float bia = bias[n];
#pragma unroll
    for (int mt = 0; mt < 4; mt++){
      f32x4 a = acc[mt][nt];
      float v = fmaxf(fmaxf(a[0], a[1]), fmaxf(a[2], a[3]));
      v = fmaxf(v, __shfl_xor(v, 16));
      v = fmaxf(v, __shfl_xor(v, 32));
      if ((lane >> 4) == 0){
        int g = groupBase + (bm >> 4) + (wm >> 4) + mt;
        pooled[(size_t)g * Nd + n] = f2bf(v + bia);
      }
    }
  }
}

// ---------------- tier fallback (f32) ----------------
__global__ __launch_bounds__(256) void fill_diag(float* __restrict__ out, size_t out_elems){
  size_t i = (size_t)blockIdx.x * 256 + threadIdx.x;
  if (i >= out_elems) return;
  size_t maskStart = (size_t)B_ * M_ * D_ + (size_t)B_ * M_ * 4;
  out[i] = (i >= maskStart) ? 1.0f : 0.0f;
}

extern "C" void kernel_launch(void* const* d_in, const int* in_sizes, int n_in,
                              void* d_out, int out_size, void* d_ws, size_t ws_size,
                              hipStream_t stream){
  (void)in_sizes; (void)n_in;
  const float* coords   = (const float*)d_in[0];
  const float* features = (const float*)d_in[1];
  const float* W0 = (const float*)d_in[2];  const float* b0 = (const float*)d_in[3];
  const float* W1 = (const float*)d_in[4];  const float* b1 = (const float*)d_in[5];
  const float* W2 = (const float*)d_in[6];  const float* b2 = (const float*)d_in[7];
  const float* W3 = (const float*)d_in[8];  const float* b3 = (const float*)d_in[9];
  const float* Wn0 = (const float*)d_in[10]; const float* bn0 = (const float*)d_in[11];
  const float* Wn1 = (const float*)d_in[12]; const float* bn1 = (const float*)d_in[13];
  float* out = (float*)d_out;
  const size_t out_elems = (size_t)out_size;

  char* ws = (char*)d_ws;
  const size_t o_cent = 0;            // 16,384 (FPS order)
  const size_t o_cntS = 16384;        // 16,384 (time order)
  const size_t o_knn  = 32768;        // 65,536 -> 98,304
  const size_t o_Wb   = 131072;       // 4,587,520 bf16 W1t..Wn1t (transposed)
  const size_t o_pool = 4718592;      // 1,572,864 bf16 [1024,768]
  const size_t o_t1   = 6291456;      // 1,572,864
  const size_t o_chunk= 7864320;      // regA (R*1536 B) + regB (R*1024 B)
  const int ROWS = B_ * M_ * K_;      // 16384

  int R = 16384;
  while (R > 128 && o_chunk + (size_t)R * 2560 > ws_size) R >>= 1;
  if (d_ws == nullptr || o_chunk + (size_t)R * 2560 > ws_size){
    fill_diag<<<(int)((out_elems + 255) / 256), 256, 0, stream>>>(out, out_elems);
    return;
  }

  float* cent_fps    = (float*)(ws + o_cent);
  float* cent_sorted = (float*)(ws + o_cntS);
  int*   knn         = (int*)(ws + o_knn);
  u16* Wb   = (u16*)(ws + o_Wb);
  u16* W1t  = Wb;               u16* W2t  = Wb + 131072;
  u16* W3t  = Wb + 524288;      u16* Wn0t = Wb + 1114112;
  u16* Wn1t = Wb + 1703936;
  u16* pooled = (u16*)(ws + o_pool);
  u16* t1     = (u16*)(ws + o_t1);
  u16* regA   = (u16*)(ws + o_chunk);                      // h1 [R,256] then h3 [R,768]
  u16* regB   = (u16*)(ws + o_chunk + (size_t)R * 1536);   // h2 [R,512]

  conv_all<<<560, 256, 0, stream>>>(W1, W2, W3, Wn0, Wn1, Wb);
  fps_block<<<B_, 1024, 0, stream>>>(coords, cent_fps);
  rank_scatter<<<B_, 128, 0, stream>>>(cent_fps, cent_sorted, out, out_elems);
  knn_kernel<<<B_ * M_, KNT, 0, stream>>>(coords, cent_sorted, knn);

  for (int rowBase = 0; rowBase < ROWS; rowBase += R){
    gather_l0<<<R / 32, 256, 0, stream>>>(features, knn, W0, b0, regA, rowBase);
    gemm_bf16<1,0><<<dim3(4, R / 128), 256, 0, stream>>>(regA, W1t, b1, regB, 256, 512);
    gemm_bf16<1,0><<<dim3(6, R / 128), 256, 0, stream>>>(regB, W2t, b2, regA, 512, 768);
    gemm_pool<<<dim3(6, R / 128), 256, 0, stream>>>(regA, W3t, b3, pooled, 768, 768, rowBase >> 4);
  }

  gemm64<1,0><<<dim3(12, (B_ * M_) / 64), 256, 0, stream>>>(pooled, Wn0t, bn0, t1, 768, 768);
  gemm64<0,1><<<dim3(12, (B_ * M_) / 64), 256, 0, stream>>>(t1, Wn1t, bn1, out, 768, 768);
}

// Round 4
// 535.311 us; speedup vs baseline: 1.1617x; 1.0312x over previous
//
#include <hip/hip_runtime.h>

#define B_ 8
#define N_ 16384
#define F_ 6
#define M_ 128
#define K_ 16
#define D_ 768

typedef unsigned short u16;
typedef unsigned int u32;
typedef unsigned long long u64;
typedef __attribute__((ext_vector_type(8))) short short8;
typedef __attribute__((ext_vector_type(4))) float f32x4;
typedef __attribute__((ext_vector_type(2))) float f32x2;

__device__ __forceinline__ u16 f2bf(float f){
  union { float f; u32 i; } v; v.f = f;
  u32 x = v.i;
  u32 r = x + 0x7FFFu + ((x >> 16) & 1u);
  return (u16)(r >> 16);
}

// async 16B global->LDS (dest = wave-uniform base + lane*16)
__device__ __forceinline__ void ld_g2l(const u16* g, u16* l){
  __builtin_amdgcn_global_load_lds((const __attribute__((address_space(1))) u32*)g,
                                   (__attribute__((address_space(3))) u32*)l, 16, 0, 0);
}

// packed dual-f32 ops (CDNA2+ full-rate packed fp32; bit-exact IEEE per lane)
__device__ __forceinline__ f32x2 pkadd(f32x2 a, f32x2 b){
  f32x2 d; asm("v_pk_add_f32 %0, %1, %2" : "=v"(d) : "v"(a), "v"(b)); return d;
}
__device__ __forceinline__ f32x2 pkmul(f32x2 a, f32x2 b){
  f32x2 d; asm("v_pk_mul_f32 %0, %1, %2" : "=v"(d) : "v"(a), "v"(b)); return d;
}

// ---------------- all weights f32 -> bf16 transposed [n][k], ONE kernel ----------------
__global__ __launch_bounds__(256) void conv_all(const float* __restrict__ W1,
                                                const float* __restrict__ W2,
                                                const float* __restrict__ W3,
                                                const float* __restrict__ Wn0,
                                                const float* __restrict__ Wn1,
                                                u16* __restrict__ Wb){
  __shared__ u16 tile[64][65];
  int blk = blockIdx.x;
  const float* W; u16* WT; int K, N, lb;
  if      (blk < 32)  { W = W1;  WT = Wb;           K = 256; N = 512; lb = blk; }
  else if (blk < 128) { W = W2;  WT = Wb + 131072;  K = 512; N = 768; lb = blk - 32; }
  else if (blk < 272) { W = W3;  WT = Wb + 524288;  K = 768; N = 768; lb = blk - 128; }
  else if (blk < 416) { W = Wn0; WT = Wb + 1114112; K = 768; N = 768; lb = blk - 272; }
  else                { W = Wn1; WT = Wb + 1703936; K = 768; N = 768; lb = blk - 416; }
  int tiles_n = N >> 6;
  int tk = lb / tiles_n, tn = lb % tiles_n;
  int k0 = tk << 6, n0 = tn << 6;
  int t = threadIdx.x;
#pragma unroll
  for (int q = 0; q < 16; q++){
    int idx = q * 256 + t;
    int kk = idx >> 6, nn = idx & 63;
    tile[kk][nn] = f2bf(W[(size_t)(k0 + kk) * N + n0 + nn]);
  }
  __syncthreads();
#pragma unroll
  for (int q = 0; q < 16; q++){
    int idx = q * 256 + t;
    int nn = idx >> 6, kk = idx & 63;
    WT[(size_t)(n0 + nn) * K + k0 + kk] = tile[kk][nn];
  }
}

// ---------------- FPS: 1 block/batch, 512 thr pinned at 2 waves/EU (256-VGPR budget) ----------------
// Thread t owns CONTIGUOUS points [32t, 32t+32) -> lane order == index order, so all
// tie-breaks (first-max, lowest index == jnp.argmax) resolve by lowest-lane ballot.
// Exact semantics: d = ((dx*dx + dy*dy) + dz*dz) + dw*dw (contract off), md = min(md, d).
// waves_per_eu(2,2) pins occupancy so the 160-VGPR point state CANNOT be rematerialized
// (rounds 0/2/3 all silently re-loaded coords from L2 every step; VGPR_Count proved it).
#define FPJ 16   // f32x2 pairs per thread: 32 points
__global__ __launch_bounds__(512) __attribute__((amdgpu_waves_per_eu(2, 2)))
void fps_block(const float* __restrict__ coords, float* __restrict__ cent){
#pragma clang fp contract(off)
  __shared__ float swv[2][8];
  __shared__ int   swi[2][8];
  int b = blockIdx.x;
  int t = threadIdx.x;
  int lane = t & 63, wave = t >> 6;
  const float* cb = coords + (size_t)b * N_ * 5;
  const int base = t << 5;                       // first point index owned by this thread
  f32x2 px[FPJ], py[FPJ], pz[FPJ], pw[FPJ], md[FPJ];
#pragma unroll
  for (int j = 0; j < FPJ; j++){
    size_t i0 = (size_t)(base + 2 * j) * 5;
    px[j] = (f32x2){cb[i0+1], cb[i0+6]};
    py[j] = (f32x2){cb[i0+2], cb[i0+7]};
    pz[j] = (f32x2){cb[i0+3], cb[i0+8]};
    pw[j] = (f32x2){cb[i0+4], cb[i0+9]};
    md[j] = (f32x2){1e30f, 1e30f};
    asm volatile("" : "+v"(px[j]), "+v"(py[j]), "+v"(pz[j]), "+v"(pw[j]));
  }
  float cx = cb[1], cy = cb[2], cz = cb[3], ct = cb[4];
  if (t == 0){
    float* c0 = cent + (size_t)b * M_ * 4;
    c0[0]=cx; c0[1]=cy; c0[2]=cz; c0[3]=ct;
  }
  for (int step = 1; step < M_; step++){
    // x - c computed as x + (-c): IEEE-identical, enables plain v_pk_add
    f32x2 ncx2 = (f32x2){-cx, -cx}, ncy2 = (f32x2){-cy, -cy};
    f32x2 ncz2 = (f32x2){-cz, -cz}, nct2 = (f32x2){-ct, -ct};
    float bv = -1.0f; int bl = 0;
#pragma unroll
    for (int j = 0; j < FPJ; j++){
      f32x2 dx = pkadd(px[j], ncx2);
      f32x2 dy = pkadd(py[j], ncy2);
      f32x2 s  = pkadd(pkmul(dx, dx), pkmul(dy, dy));   // dx*dx + dy*dy (one rounding per op)
      f32x2 dz = pkadd(pz[j], ncz2);
      s = pkadd(s, pkmul(dz, dz));                      // + dz*dz
      f32x2 dw = pkadd(pw[j], nct2);
      s = pkadd(s, pkmul(dw, dw));                      // + dw*dw
      f32x2 m = md[j];
      m[0] = fminf(s[0], m[0]);
      m[1] = fminf(s[1], m[1]);
      md[j] = m;
      // local offsets are small compile-time consts -> inline-operand cndmasks
      if (m[0] > bv){ bv = m[0]; bl = 2*j;     }        // ascending-index first-max
      if (m[1] > bv){ bv = m[1]; bl = 2*j + 1; }
    }
    int bi = base + bl;                                 // global point index
    // wave argmax: value-only f32 butterfly, then lowest-lane ballot (lane order==index order)
    float wv = bv;
#pragma unroll
    for (int off = 1; off < 64; off <<= 1) wv = fmaxf(wv, __shfl_xor(wv, off));
    u64 wm = __ballot(bv == wv);
    int srcL = (int)__ffsll((unsigned long long)wm) - 1;
    int wbi = __shfl(bi, srcL);
    int par = step & 1;
    if (lane == 0){ swv[par][wave] = wv; swi[par][wave] = wbi; }
    __syncthreads();                                    // only barrier per step
    // block combine over 8 wave results: lanes replicate mod 8; 3-level xor max + ballot
    float v8 = swv[par][lane & 7];
    int   i8 = swi[par][lane & 7];
    float g = v8;
    g = fmaxf(g, __shfl_xor(g, 1));
    g = fmaxf(g, __shfl_xor(g, 2));
    g = fmaxf(g, __shfl_xor(g, 4));
    u64 bm = __ballot((lane < 8) && (v8 == g));
    int srcW = (int)__ffsll((unsigned long long)bm) - 1;
    int widx = __builtin_amdgcn_readfirstlane(__shfl(i8, srcW));
    size_t wb = (size_t)widx * 5;
    cx = cb[wb+1]; cy = cb[wb+2]; cz = cb[wb+3]; ct = cb[wb+4];
    if (t == 0){
      float* cr = cent + ((size_t)b * M_ + step) * 4;
      cr[0]=cx; cr[1]=cy; cr[2]=cz; cr[3]=ct;
    }
  }
}

// ---------------- stable rank by centroid time; relabel early; f32 outputs ----------------
__global__ __launch_bounds__(128) void rank_scatter(const float* __restrict__ cent_fps,
                                                    float* __restrict__ cent_sorted,
                                                    float* __restrict__ out,
                                                    size_t out_elems){
  int b = blockIdx.x, m = threadIdx.x;
  __shared__ float tt[M_];
  const float* row = cent_fps + ((size_t)b * M_ + m) * 4;
  float x=row[0], y=row[1], z=row[2], w=row[3];
  tt[m] = w;
  __syncthreads();
  int rank = 0;
  for (int j = 0; j < M_; j++){
    float tj = tt[j];
    if (tj < w || (tj == w && j < m)) rank++;       // stable argsort semantics
  }
  float* dst = cent_sorted + ((size_t)b * M_ + rank) * 4;
  dst[0]=x; dst[1]=y; dst[2]=z; dst[3]=w;
  size_t co = (size_t)B_ * M_ * D_ + ((size_t)b * M_ + rank) * 4;
  if (co + 3 < out_elems){
    out[co+0]=x; out[co+1]=y; out[co+2]=z; out[co+3]=w;
  }
  size_t mo = (size_t)B_ * M_ * D_ + (size_t)B_ * M_ * 4 + (size_t)b * M_ + m;
  if (mo < out_elems) out[mo] = 1.0f;              // mask = True -> 1.0f
}

// ---------------- kNN: f32, np op order, stable-min extraction ----------------
#define KNT 512
#define KPT 32
__global__ __launch_bounds__(512) void knn_kernel(const float* __restrict__ coords,
                                                  const float* __restrict__ cent,
                                                  int* __restrict__ knn){
#pragma clang fp contract(off)
  int cm = blockIdx.x;
  int b = cm >> 7;
  const float* cb = coords + (size_t)b * N_ * 5;
  int t = threadIdx.x;
  float cx=cent[cm*4+0], cy=cent[cm*4+1], cz=cent[cm*4+2], ct=cent[cm*4+3];
  float dist[KPT];
#pragma unroll
  for (int j = 0; j < KPT; j++){
    size_t i = t + j * KNT;
    float dx=cb[i*5+1]-cx, dy=cb[i*5+2]-cy, dz=cb[i*5+3]-cz, dw=cb[i*5+4]-ct;
    float d = ((dx*dx + dy*dy) + dz*dz) + dw*dw;
    dist[j] = sqrtf(d);                            // IEEE f32 sqrt = np.sqrt(f32)
  }
  __shared__ float s_wv[8];
  __shared__ int s_wi[8];
  __shared__ int s_bi;
  for (int r = 0; r < K_; r++){
    float bv = 3e38f; int bi = 1 << 30;
#pragma unroll
    for (int j = 0; j < KPT; j++){
      int i = t + j * KNT;
      float v = dist[j];
      if (v < bv){ bv = v; bi = i; }               // first-min kept
    }
#pragma unroll
    for (int off = 32; off > 0; off >>= 1){
      float ov = __shfl_down(bv, off);
      int oi = __shfl_down(bi, off);
      if (ov < bv || (ov == bv && oi < bi)){ bv = ov; bi = oi; }
    }
    if ((t & 63) == 0){ s_wv[t >> 6] = bv; s_wi[t >> 6] = bi; }
    __syncthreads();
    if (t == 0){
      float fv = s_wv[0]; int fi = s_wi[0];
      for (int w = 1; w < 8; w++){
        float wv = s_wv[w]; int wi = s_wi[w];
        if (wv < fv || (wv == fv && wi < fi)){ fv = wv; fi = wi; }
      }
      s_bi = fi;
      knn[(size_t)cm * K_ + r] = fi & (N_ - 1);
    }
    __syncthreads();
    int wi = s_bi;
#pragma unroll
    for (int j = 0; j < KPT; j++){
      if (t + j * KNT == wi) dist[j] = 3e38f;
    }
  }
}

// ---------------- gather + layer0: 32 rows/block, W0/b0/features LDS-staged ----------------
__global__ __launch_bounds__(256) void gather_l0(const float* __restrict__ feat,
                                                 const int* __restrict__ knn,
                                                 const float* __restrict__ W0,
                                                 const float* __restrict__ b0,
                                                 u16* __restrict__ h1,
                                                 int rowBase){
  __shared__ float sW[F_][256];
  __shared__ float sb[256];
  __shared__ float sfa[32][F_];
  int t = threadIdx.x;
#pragma unroll
  for (int k = 0; k < F_; k++) sW[k][t] = W0[k * 256 + t];
  sb[t] = b0[t];
  if (t < 32 * F_){
    int r = t / F_, k = t % F_;
    int grow = rowBase + blockIdx.x * 32 + r;
    int bb = grow >> 11;                          // /(M*K)=2048
    int idx = knn[grow] & (N_ - 1);
    sfa[r][k] = feat[((size_t)bb * N_ + idx) * F_ + k];
  }
  __syncthreads();
#pragma unroll 4
  for (int r = 0; r < 32; r++){
    float acc = sb[t];
#pragma unroll
    for (int k = 0; k < F_; k++) acc = fmaf(sfa[r][k], sW[k][t], acc);
    int lrow = blockIdx.x * 32 + r;
    h1[(size_t)lrow * 256 + t] = f2bf(fmaxf(acc, 0.0f));
  }
}

// ---------------- bf16 MFMA GEMM (128x128), async global->LDS staging ----------------
// Unpadded [128][32] rows (64B): dest = wave-uniform base + lane*16 (m97 layout).
template<int RELU, int OUTF32>
__global__ __launch_bounds__(256) void gemm_bf16(const u16* __restrict__ A,
                                                 const u16* __restrict__ WT,
                                                 const float* __restrict__ bias,
                                                 void* __restrict__ Cv,
                                                 int Kd, int Nd){
  __shared__ u16 As[128][32];
  __shared__ u16 Bs[128][32];
  const int t = threadIdx.x;
  const int bm = blockIdx.y << 7;
  const int bn = blockIdx.x << 7;
  const int wave = t >> 6;
  const int lane = t & 63;
  const int wm = (wave & 1) << 6;
  const int wn = (wave >> 1) << 6;
  const int lm = lane & 15;
  const int lk = (lane >> 4) << 3;
  u16* AsF = &As[0][0];
  u16* BsF = &Bs[0][0];
  const int wbase = wave << 6;               // t - lane
  f32x4 acc[4][4] = {};
  for (int k0 = 0; k0 < Kd; k0 += 32){
#pragma unroll
    for (int it = 0; it < 2; it++){
      int slot = t + (it << 8);
      int r = slot >> 2;
      int c = (slot & 3) << 3;
      int dst = (wbase + (it << 8)) << 3;    // u16 elements; +lane*16B by HW
      ld_g2l(A  + (size_t)(bm + r) * Kd + k0 + c, AsF + dst);
      ld_g2l(WT + (size_t)(bn + r) * Kd + k0 + c, BsF + dst);
    }
    __syncthreads();
    short8 af[4], bfr[4];
#pragma unroll
    for (int mt = 0; mt < 4; mt++) af[mt] = *(const short8*)&As[wm + (mt << 4) + lm][lk];
#pragma unroll
    for (int nt = 0; nt < 4; nt++) bfr[nt] = *(const short8*)&Bs[wn + (nt << 4) + lm][lk];
#pragma unroll
    for (int mt = 0; mt < 4; mt++)
#pragma unroll
      for (int nt = 0; nt < 4; nt++)
        acc[mt][nt] = __builtin_amdgcn_mfma_f32_16x16x32_bf16(af[mt], bfr[nt], acc[mt][nt], 0, 0, 0);
    __syncthreads();
  }
#pragma unroll
  for (int nt = 0; nt < 4; nt++){
    int n = bn + wn + (nt << 4) + lm;
    float bia = bias[n];
#pragma unroll
    for (int mt = 0; mt < 4; mt++){
#pragma unroll
      for (int r2 = 0; r2 < 4; r2++){
        int m = bm + wm + (mt << 4) + ((lane >> 4) << 2) + r2;
        float v = acc[mt][nt][r2] + bia;
        if (RELU) v = fmaxf(v, 0.0f);
        if (OUTF32) ((float*)Cv)[(size_t)m * Nd + n] = v;
        else        ((u16*)Cv)[(size_t)m * Nd + n] = f2bf(v);
      }
    }
  }
}

// ---------------- bf16 MFMA GEMM (64x64), async staging, token GEMMs ----------------
template<int RELU, int OUTF32>
__global__ __launch_bounds__(256) void gemm64(const u16* __restrict__ A,
                                              const u16* __restrict__ WT,
                                              const float* __restrict__ bias,
                                              void* __restrict__ Cv,
                                              int Kd, int Nd){
  __shared__ u16 As[64][32];
  __shared__ u16 Bs[64][32];
  const int t = threadIdx.x;
  const int bm = blockIdx.y << 6;
  const int bn = blockIdx.x << 6;
  const int wave = t >> 6;
  const int lane = t & 63;
  const int wm = (wave & 1) << 5;
  const int wn = (wave >> 1) << 5;
  const int lm = lane & 15;
  const int lk = (lane >> 4) << 3;
  u16* AsF = &As[0][0];
  u16* BsF = &Bs[0][0];
  const int wbase = wave << 6;
  f32x4 acc[2][2] = {};
  for (int k0 = 0; k0 < Kd; k0 += 32){
    {
      int r = t >> 2;
      int c = (t & 3) << 3;
      int dst = wbase << 3;
      ld_g2l(A  + (size_t)(bm + r) * Kd + k0 + c, AsF + dst);
      ld_g2l(WT + (size_t)(bn + r) * Kd + k0 + c, BsF + dst);
    }
    __syncthreads();
    short8 af[2], bfr[2];
#pragma unroll
    for (int mt = 0; mt < 2; mt++) af[mt] = *(const short8*)&As[wm + (mt << 4) + lm][lk];
#pragma unroll
    for (int nt = 0; nt < 2; nt++) bfr[nt] = *(const short8*)&Bs[wn + (nt << 4) + lm][lk];
#pragma unroll
    for (int mt = 0; mt < 2; mt++)
#pragma unroll
      for (int nt = 0; nt < 2; nt++)
        acc[mt][nt] = __builtin_amdgcn_mfma_f32_16x16x32_bf16(af[mt], bfr[nt], acc[mt][nt], 0, 0, 0);
    __syncthreads();
  }
#pragma unroll
  for (int nt = 0; nt < 2; nt++){
    int n = bn + wn + (nt << 4) + lm;
    float bia = bias[n];
#pragma unroll
    for (int mt = 0; mt < 2; mt++){
#pragma unroll
      for (int r2 = 0; r2 < 4; r2++){
        int m = bm + wm + (mt << 4) + ((lane >> 4) << 2) + r2;
        float v = acc[mt][nt][r2] + bia;
        if (RELU) v = fmaxf(v, 0.0f);
        if (OUTF32) ((float*)Cv)[(size_t)m * Nd + n] = v;
        else        ((u16*)Cv)[(size_t)m * Nd + n] = f2bf(v);
      }
    }
  }
}

// ---------------- GEMM + fused max-pool (128x128), async staging ----------------
__global__ __launch_bounds__(256) void gemm_pool(const u16* __restrict__ A,
                                                 const u16* __restrict__ WT,
                                                 const float* __restrict__ bias,
                                                 u16* __restrict__ pooled,
                                                 int Kd, int Nd, int groupBase){
  __shared__ u16 As[128][32];
  __shared__ u16 Bs[128][32];
  const int t = threadIdx.x;
  const int bm = blockIdx.y << 7;
  const int bn = blockIdx.x << 7;
  const int wave = t >> 6;
  const int lane = t & 63;
  const int wm = (wave & 1) << 6;
  const int wn = (wave >> 1) << 6;
  const int lm = lane & 15;
  const int lk = (lane >> 4) << 3;
  u16* AsF = &As[0][0];
  u16* BsF = &Bs[0][0];
  const int wbase = wave << 6;
  f32x4 acc[4][4] = {};
  for (int k0 = 0; k0 < Kd; k0 += 32){
#pragma unroll
    for (int it = 0; it < 2; it++){
      int slot = t + (it << 8);
      int r = slot >> 2;
      int c = (slot & 3) << 3;
      int dst = (wbase + (it << 8)) << 3;
      ld_g2l(A  + (size_t)(bm + r) * Kd + k0 + c, AsF + dst);
      ld_g2l(WT + (size_t)(bn + r) * Kd + k0 + c, BsF + dst);
    }
    __syncthreads();
    short8 af[4], bfr[4];
#pragma unroll
    for (int mt = 0; mt < 4; mt++) af[mt] = *(const short8*)&As[wm + (mt << 4) + lm][lk];
#pragma unroll
    for (int nt = 0; nt < 4; nt++) bfr[nt] = *(const short8*)&Bs[wn + (nt << 4) + lm][lk];
#pragma unroll
    for (int mt = 0; mt < 4; mt++)
#pragma unroll
      for (int nt = 0; nt < 4; nt++)
        acc[mt][nt] = __builtin_amdgcn_mfma_f32_16x16x32_bf16(af[mt], bfr[nt], acc[mt][nt], 0, 0, 0);
    __syncthreads();
  }
  // each (mt) tile's 16 rows are exactly one pooling group
#pragma unroll
  for (int nt = 0; nt < 4; nt++){
    int n = bn + wn + (nt << 4) + lm;
    float bia = bias[n];
#pragma unroll
    for (int mt = 0; mt < 4; mt++){
      f32x4 a = acc[mt][nt];
      float v = fmaxf(fmaxf(a[0], a[1]), fmaxf(a[2], a[3]));
      v = fmaxf(v, __shfl_xor(v, 16));
      v = fmaxf(v, __shfl_xor(v, 32));
      if ((lane >> 4) == 0){
        int g = groupBase + (bm >> 4) + (wm >> 4) + mt;
        pooled[(size_t)g * Nd + n] = f2bf(v + bia);
      }
    }
  }
}

// ---------------- tier fallback (f32) ----------------
__global__ __launch_bounds__(256) void fill_diag(float* __restrict__ out, size_t out_elems){
  size_t i = (size_t)blockIdx.x * 256 + threadIdx.x;
  if (i >= out_elems) return;
  size_t maskStart = (size_t)B_ * M_ * D_ + (size_t)B_ * M_ * 4;
  out[i] = (i >= maskStart) ? 1.0f : 0.0f;
}

extern "C" void kernel_launch(void* const* d_in, const int* in_sizes, int n_in,
                              void* d_out, int out_size, void* d_ws, size_t ws_size,
                              hipStream_t stream){
  (void)in_sizes; (void)n_in;
  const float* coords   = (const float*)d_in[0];
  const float* features = (const float*)d_in[1];
  const float* W0 = (const float*)d_in[2];  const float* b0 = (const float*)d_in[3];
  const float* W1 = (const float*)d_in[4];  const float* b1 = (const float*)d_in[5];
  const float* W2 = (const float*)d_in[6];  const float* b2 = (const float*)d_in[7];
  const float* W3 = (const float*)d_in[8];  const float* b3 = (const float*)d_in[9];
  const float* Wn0 = (const float*)d_in[10]; const float* bn0 = (const float*)d_in[11];
  const float* Wn1 = (const float*)d_in[12]; const float* bn1 = (const float*)d_in[13];
  float* out = (float*)d_out;
  const size_t out_elems = (size_t)out_size;

  char* ws = (char*)d_ws;
  const size_t o_cent = 0;            // 16,384 (FPS order)
  const size_t o_cntS = 16384;        // 16,384 (time order)
  const size_t o_knn  = 32768;        // 65,536 -> 98,304
  const size_t o_Wb   = 131072;       // 4,587,520 bf16 W1t..Wn1t (transposed)
  const size_t o_pool = 4718592;      // 1,572,864 bf16 [1024,768]
  const size_t o_t1   = 6291456;      // 1,572,864
  const size_t o_chunk= 7864320;      // regA (R*1536 B) + regB (R*1024 B)
  const int ROWS = B_ * M_ * K_;      // 16384

  int R = 16384;
  while (R > 128 && o_chunk + (size_t)R * 2560 > ws_size) R >>= 1;
  if (d_ws == nullptr || o_chunk + (size_t)R * 2560 > ws_size){
    fill_diag<<<(int)((out_elems + 255) / 256), 256, 0, stream>>>(out, out_elems);
    return;
  }

  float* cent_fps    = (float*)(ws + o_cent);
  float* cent_sorted = (float*)(ws + o_cntS);
  int*   knn         = (int*)(ws + o_knn);
  u16* Wb   = (u16*)(ws + o_Wb);
  u16* W1t  = Wb;               u16* W2t  = Wb + 131072;
  u16* W3t  = Wb + 524288;      u16* Wn0t = Wb + 1114112;
  u16* Wn1t = Wb + 1703936;
  u16* pooled = (u16*)(ws + o_pool);
  u16* t1     = (u16*)(ws + o_t1);
  u16* regA   = (u16*)(ws + o_chunk);                      // h1 [R,256] then h3 [R,768]
  u16* regB   = (u16*)(ws + o_chunk + (size_t)R * 1536);   // h2 [R,512]

  conv_all<<<560, 256, 0, stream>>>(W1, W2, W3, Wn0, Wn1, Wb);
  fps_block<<<B_, 512, 0, stream>>>(coords, cent_fps);
  rank_scatter<<<B_, 128, 0, stream>>>(cent_fps, cent_sorted, out, out_elems);
  knn_kernel<<<B_ * M_, KNT, 0, stream>>>(coords, cent_sorted, knn);

  for (int rowBase = 0; rowBase < ROWS; rowBase += R){
    gather_l0<<<R / 32, 256, 0, stream>>>(features, knn, W0, b0, regA, rowBase);
    gemm_bf16<1,0><<<dim3(4, R / 128), 256, 0, stream>>>(regA, W1t, b1, regB, 256, 512);
    gemm_bf16<1,0><<<dim3(6, R / 128), 256, 0, stream>>>(regB, W2t, b2, regA, 512, 768);
    gemm_pool<<<dim3(6, R / 128), 256, 0, stream>>>(regA, W3t, b3, pooled, 768, 768, rowBase >> 4);
  }

  gemm64<1,0><<<dim3(12, (B_ * M_) / 64), 256, 0, stream>>>(pooled, Wn0t, bn0, t1, 768, 768);
  gemm64<0,1><<<dim3(12, (B_ * M_) / 64), 256, 0, stream>>>(t1, Wn1t, bn1, out, 768, 768);
}

// Round 6
// 520.309 us; speedup vs baseline: 1.1951x; 1.0288x over previous
//
#include <hip/hip_runtime.h>

#define B_ 8
#define N_ 16384
#define F_ 6
#define M_ 128
#define K_ 16
#define D_ 768

typedef unsigned short u16;
typedef unsigned int u32;
typedef unsigned long long u64;
typedef __attribute__((ext_vector_type(8))) short short8;
typedef __attribute__((ext_vector_type(4))) float f32x4;
typedef __attribute__((ext_vector_type(2))) float f32x2;

__device__ __forceinline__ u16 f2bf(float f){
  union { float f; u32 i; } v; v.f = f;
  u32 x = v.i;
  u32 r = x + 0x7FFFu + ((x >> 16) & 1u);
  return (u16)(r >> 16);
}

// async 16B global->LDS (dest = wave-uniform base + lane*16)
__device__ __forceinline__ void ld_g2l(const u16* g, u16* l){
  __builtin_amdgcn_global_load_lds((const __attribute__((address_space(1))) u32*)g,
                                   (__attribute__((address_space(3))) u32*)l, 16, 0, 0);
}

// packed dual-f32 ops (CDNA2+ full-rate packed fp32; bit-exact IEEE per lane)
__device__ __forceinline__ f32x2 pkadd(f32x2 a, f32x2 b){
  f32x2 d; asm("v_pk_add_f32 %0, %1, %2" : "=v"(d) : "v"(a), "v"(b)); return d;
}
__device__ __forceinline__ f32x2 pkmul(f32x2 a, f32x2 b){
  f32x2 d; asm("v_pk_mul_f32 %0, %1, %2" : "=v"(d) : "v"(a), "v"(b)); return d;
}

// DPP self-max step: v = max(v, lane-shifted v). Full-rate VALU — no LDS, no lgkmcnt.
// bound-invalid lanes keep old (=self): harmless for max. CDNA keeps gfx9 row_bcast.
template<int CTRL>
__device__ __forceinline__ float dppmax(float v){
  union { float f; int i; } a, r;
  a.f = v;
  r.i = __builtin_amdgcn_update_dpp(a.i, a.i, CTRL, 0xF, 0xF, false);
  return fmaxf(v, r.f);
}

// ---------------- all weights f32 -> bf16 transposed [n][k], ONE kernel ----------------
__global__ __launch_bounds__(256) void conv_all(const float* __restrict__ W1,
                                                const float* __restrict__ W2,
                                                const float* __restrict__ W3,
                                                const float* __restrict__ Wn0,
                                                const float* __restrict__ Wn1,
                                                u16* __restrict__ Wb){
  __shared__ u16 tile[64][65];
  int blk = blockIdx.x;
  const float* W; u16* WT; int K, N, lb;
  if      (blk < 32)  { W = W1;  WT = Wb;           K = 256; N = 512; lb = blk; }
  else if (blk < 128) { W = W2;  WT = Wb + 131072;  K = 512; N = 768; lb = blk - 32; }
  else if (blk < 272) { W = W3;  WT = Wb + 524288;  K = 768; N = 768; lb = blk - 128; }
  else if (blk < 416) { W = Wn0; WT = Wb + 1114112; K = 768; N = 768; lb = blk - 272; }
  else                { W = Wn1; WT = Wb + 1703936; K = 768; N = 768; lb = blk - 416; }
  int tiles_n = N >> 6;
  int tk = lb / tiles_n, tn = lb % tiles_n;
  int k0 = tk << 6, n0 = tn << 6;
  int t = threadIdx.x;
#pragma unroll
  for (int q = 0; q < 16; q++){
    int idx = q * 256 + t;
    int kk = idx >> 6, nn = idx & 63;
    tile[kk][nn] = f2bf(W[(size_t)(k0 + kk) * N + n0 + nn]);
  }
  __syncthreads();
#pragma unroll
  for (int q = 0; q < 16; q++){
    int idx = q * 256 + t;
    int nn = idx >> 6, kk = idx & 63;
    WT[(size_t)(n0 + nn) * K + k0 + kk] = tile[kk][nn];
  }
}

// ---------------- FPS: 1 block/batch; DPP wave-argmax + scalar combine (no bpermute) ----------------
// Thread t owns CONTIGUOUS points [32t, 32t+32) -> lane order == index order, so all
// tie-breaks (first-max, lowest index == jnp.argmax) resolve by lowest-lane ballot.
// Exact semantics: d = ((dx*dx + dy*dy) + dz*dz) + dw*dw (contract off), md = min(md, d).
// r0-r4 lesson: the step cost was NOT the md-update loop (4 rewrites, all ~2.2us/step);
// it was the reduce tail: ~12 dependent ds_bpermute shuffles (~150cy each at 2 waves/SIMD).
// This version: 6 DPP fmax (VALU) + readlane/ballot (scalar) + 1 LDS publish round.
#define FPJ 16   // f32x2 pairs per thread: 32 points
__global__ __launch_bounds__(512) __attribute__((amdgpu_waves_per_eu(2, 2)))
void fps_block(const float* __restrict__ coords, float* __restrict__ cent){
#pragma clang fp contract(off)
  __shared__ float swv[2][8];
  __shared__ int   swi[2][8];
  int b = blockIdx.x;
  int t = threadIdx.x;
  int lane = t & 63, wave = t >> 6;
  const float* cb = coords + (size_t)b * N_ * 5;
  const int base = t << 5;                       // first point index owned by this thread
  f32x2 px[FPJ], py[FPJ], pz[FPJ], pw[FPJ], md[FPJ];
#pragma unroll
  for (int j = 0; j < FPJ; j++){
    size_t i0 = (size_t)(base + 2 * j) * 5;
    px[j] = (f32x2){cb[i0+1], cb[i0+6]};
    py[j] = (f32x2){cb[i0+2], cb[i0+7]};
    pz[j] = (f32x2){cb[i0+3], cb[i0+8]};
    pw[j] = (f32x2){cb[i0+4], cb[i0+9]};
    md[j] = (f32x2){1e30f, 1e30f};
    asm volatile("" : "+v"(px[j]), "+v"(py[j]), "+v"(pz[j]), "+v"(pw[j]));
  }
  float cx = cb[1], cy = cb[2], cz = cb[3], ct = cb[4];
  if (t == 0){
    float* c0 = cent + (size_t)b * M_ * 4;
    c0[0]=cx; c0[1]=cy; c0[2]=cz; c0[3]=ct;
  }
  for (int step = 1; step < M_; step++){
    // x - c computed as x + (-c): IEEE-identical, enables plain v_pk_add
    f32x2 ncx2 = (f32x2){-cx, -cx}, ncy2 = (f32x2){-cy, -cy};
    f32x2 ncz2 = (f32x2){-cz, -cz}, nct2 = (f32x2){-ct, -ct};
    float bv = -1.0f; int bl = 0;
#pragma unroll
    for (int j = 0; j < FPJ; j++){
      f32x2 dx = pkadd(px[j], ncx2);
      f32x2 dy = pkadd(py[j], ncy2);
      f32x2 s  = pkadd(pkmul(dx, dx), pkmul(dy, dy));   // dx*dx + dy*dy (one rounding per op)
      f32x2 dz = pkadd(pz[j], ncz2);
      s = pkadd(s, pkmul(dz, dz));                      // + dz*dz
      f32x2 dw = pkadd(pw[j], nct2);
      s = pkadd(s, pkmul(dw, dw));                      // + dw*dw
      f32x2 m = md[j];
      m[0] = fminf(s[0], m[0]);
      m[1] = fminf(s[1], m[1]);
      md[j] = m;
      // local offsets are small compile-time consts -> inline-operand cndmasks
      if (m[0] > bv){ bv = m[0]; bl = 2*j;     }        // ascending-index first-max
      if (m[1] > bv){ bv = m[1]; bl = 2*j + 1; }
    }
    int bi = base + bl;                                 // global point index
    // ---- wave argmax: 6 DPP fmax levels -> lane 63 holds wave max ----
    float r = bv;
    r = dppmax<0x111>(r);        // row_shr:1
    r = dppmax<0x112>(r);        // row_shr:2
    r = dppmax<0x114>(r);        // row_shr:4
    r = dppmax<0x118>(r);        // row_shr:8
    r = dppmax<0x142>(r);        // row_bcast:15
    r = dppmax<0x143>(r);        // row_bcast:31
    union { float f; int i; } rm; rm.f = r;
    union { int i; float f; } wmu; wmu.i = __builtin_amdgcn_readlane(rm.i, 63);
    float wmax = wmu.f;                                 // uniform (SGPR)
    u64 wmask = __ballot(bv == wmax);
    int srcL = (int)__ffsll((unsigned long long)wmask) - 1;  // lowest lane = lowest index
    int wbi = __builtin_amdgcn_readlane(bi, srcL);      // uniform winner index of this wave
    int par = step & 1;
    if (lane == 0){ swv[par][wave] = wmax; swi[par][wave] = wbi; }
    __syncthreads();                                    // only barrier per step
    // ---- block combine: broadcast LDS reads + uniform serial strict-greater scan ----
    float fv = swv[par][0]; int fi = swi[par][0];
#pragma unroll
    for (int w = 1; w < 8; w++){
      float v = swv[par][w];
      int  iw = swi[par][w];
      if (v > fv){ fv = v; fi = iw; }                   // strict > keeps lowest wave (= lowest index)
    }
    int widx = __builtin_amdgcn_readfirstlane(fi);
    size_t wb = (size_t)widx * 5;
    cx = cb[wb+1]; cy = cb[wb+2]; cz = cb[wb+3]; ct = cb[wb+4];
    if (t == 0){
      float* cr = cent + ((size_t)b * M_ + step) * 4;
      cr[0]=cx; cr[1]=cy; cr[2]=cz; cr[3]=ct;
    }
  }
}

// ---------------- stable rank by centroid time; relabel early; f32 outputs ----------------
__global__ __launch_bounds__(128) void rank_scatter(const float* __restrict__ cent_fps,
                                                    float* __restrict__ cent_sorted,
                                                    float* __restrict__ out,
                                                    size_t out_elems){
  int b = blockIdx.x, m = threadIdx.x;
  __shared__ float tt[M_];
  const float* row = cent_fps + ((size_t)b * M_ + m) * 4;
  float x=row[0], y=row[1], z=row[2], w=row[3];
  tt[m] = w;
  __syncthreads();
  int rank = 0;
  for (int j = 0; j < M_; j++){
    float tj = tt[j];
    if (tj < w || (tj == w && j < m)) rank++;       // stable argsort semantics
  }
  float* dst = cent_sorted + ((size_t)b * M_ + rank) * 4;
  dst[0]=x; dst[1]=y; dst[2]=z; dst[3]=w;
  size_t co = (size_t)B_ * M_ * D_ + ((size_t)b * M_ + rank) * 4;
  if (co + 3 < out_elems){
    out[co+0]=x; out[co+1]=y; out[co+2]=z; out[co+3]=w;
  }
  size_t mo = (size_t)B_ * M_ * D_ + (size_t)B_ * M_ * 4 + (size_t)b * M_ + m;
  if (mo < out_elems) out[mo] = 1.0f;              // mask = True -> 1.0f
}

// ---------------- kNN: f32, np op order, stable-min extraction ----------------
#define KNT 512
#define KPT 32
__global__ __launch_bounds__(512) void knn_kernel(const float* __restrict__ coords,
                                                  const float* __restrict__ cent,
                                                  int* __restrict__ knn){
#pragma clang fp contract(off)
  int cm = blockIdx.x;
  int b = cm >> 7;
  const float* cb = coords + (size_t)b * N_ * 5;
  int t = threadIdx.x;
  float cx=cent[cm*4+0], cy=cent[cm*4+1], cz=cent[cm*4+2], ct=cent[cm*4+3];
  float dist[KPT];
#pragma unroll
  for (int j = 0; j < KPT; j++){
    size_t i = t + j * KNT;
    float dx=cb[i*5+1]-cx, dy=cb[i*5+2]-cy, dz=cb[i*5+3]-cz, dw=cb[i*5+4]-ct;
    float d = ((dx*dx + dy*dy) + dz*dz) + dw*dw;
    dist[j] = sqrtf(d);                            // IEEE f32 sqrt = np.sqrt(f32)
  }
  __shared__ float s_wv[8];
  __shared__ int s_wi[8];
  __shared__ int s_bi;
  for (int r = 0; r < K_; r++){
    float bv = 3e38f; int bi = 1 << 30;
#pragma unroll
    for (int j = 0; j < KPT; j++){
      int i = t + j * KNT;
      float v = dist[j];
      if (v < bv){ bv = v; bi = i; }               // first-min kept
    }
#pragma unroll
    for (int off = 32; off > 0; off >>= 1){
      float ov = __shfl_down(bv, off);
      int oi = __shfl_down(bi, off);
      if (ov < bv || (ov == bv && oi < bi)){ bv = ov; bi = oi; }
    }
    if ((t & 63) == 0){ s_wv[t >> 6] = bv; s_wi[t >> 6] = bi; }
    __syncthreads();
    if (t == 0){
      float fv = s_wv[0]; int fi = s_wi[0];
      for (int w = 1; w < 8; w++){
        float wv = s_wv[w]; int wi = s_wi[w];
        if (wv < fv || (wv == fv && wi < fi)){ fv = wv; fi = wi; }
      }
      s_bi = fi;
      knn[(size_t)cm * K_ + r] = fi & (N_ - 1);
    }
    __syncthreads();
    int wi = s_bi;
#pragma unroll
    for (int j = 0; j < KPT; j++){
      if (t + j * KNT == wi) dist[j] = 3e38f;
    }
  }
}

// ---------------- gather + layer0: 32 rows/block, W0/b0/features LDS-staged ----------------
__global__ __launch_bounds__(256) void gather_l0(const float* __restrict__ feat,
                                                 const int* __restrict__ knn,
                                                 const float* __restrict__ W0,
                                                 const float* __restrict__ b0,
                                                 u16* __restrict__ h1,
                                                 int rowBase){
  __shared__ float sW[F_][256];
  __shared__ float sb[256];
  __shared__ float sfa[32][F_];
  int t = threadIdx.x;
#pragma unroll
  for (int k = 0; k < F_; k++) sW[k][t] = W0[k * 256 + t];
  sb[t] = b0[t];
  if (t < 32 * F_){
    int r = t / F_, k = t % F_;
    int grow = rowBase + blockIdx.x * 32 + r;
    int bb = grow >> 11;                          // /(M*K)=2048
    int idx = knn[grow] & (N_ - 1);
    sfa[r][k] = feat[((size_t)bb * N_ + idx) * F_ + k];
  }
  __syncthreads();
#pragma unroll 4
  for (int r = 0; r < 32; r++){
    float acc = sb[t];
#pragma unroll
    for (int k = 0; k < F_; k++) acc = fmaf(sfa[r][k], sW[k][t], acc);
    int lrow = blockIdx.x * 32 + r;
    h1[(size_t)lrow * 256 + t] = f2bf(fmaxf(acc, 0.0f));
  }
}

// ---------------- bf16 MFMA GEMM (128x128), async global->LDS staging ----------------
// Unpadded [128][32] rows (64B): dest = wave-uniform base + lane*16 (m97 layout).
template<int RELU, int OUTF32>
__global__ __launch_bounds__(256) void gemm_bf16(const u16* __restrict__ A,
                                                 const u16* __restrict__ WT,
                                                 const float* __restrict__ bias,
                                                 void* __restrict__ Cv,
                                                 int Kd, int Nd){
  __shared__ u16 As[128][32];
  __shared__ u16 Bs[128][32];
  const int t = threadIdx.x;
  const int bm = blockIdx.y << 7;
  const int bn = blockIdx.x << 7;
  const int wave = t >> 6;
  const int lane = t & 63;
  const int wm = (wave & 1) << 6;
  const int wn = (wave >> 1) << 6;
  const int lm = lane & 15;
  const int lk = (lane >> 4) << 3;
  u16* AsF = &As[0][0];
  u16* BsF = &Bs[0][0];
  const int wbase = wave << 6;               // t - lane
  f32x4 acc[4][4] = {};
  for (int k0 = 0; k0 < Kd; k0 += 32){
#pragma unroll
    for (int it = 0; it < 2; it++){
      int slot = t + (it << 8);
      int r = slot >> 2;
      int c = (slot & 3) << 3;
      int dst = (wbase + (it << 8)) << 3;    // u16 elements; +lane*16B by HW
      ld_g2l(A  + (size_t)(bm + r) * Kd + k0 + c, AsF + dst);
      ld_g2l(WT + (size_t)(bn + r) * Kd + k0 + c, BsF + dst);
    }
    __syncthreads();
    short8 af[4], bfr[4];
#pragma unroll
    for (int mt = 0; mt < 4; mt++) af[mt] = *(const short8*)&As[wm + (mt << 4) + lm][lk];
#pragma unroll
    for (int nt = 0; nt < 4; nt++) bfr[nt] = *(const short8*)&Bs[wn + (nt << 4) + lm][lk];
#pragma unroll
    for (int mt = 0; mt < 4; mt++)
#pragma unroll
      for (int nt = 0; nt < 4; nt++)
        acc[mt][nt] = __builtin_amdgcn_mfma_f32_16x16x32_bf16(af[mt], bfr[nt], acc[mt][nt], 0, 0, 0);
    __syncthreads();
  }
#pragma unroll
  for (int nt = 0; nt < 4; nt++){
    int n = bn + wn + (nt << 4) + lm;
    float bia = bias[n];
#pragma unroll
    for (int mt = 0; mt < 4; mt++){
#pragma unroll
      for (int r2 = 0; r2 < 4; r2++){
        int m = bm + wm + (mt << 4) + ((lane >> 4) << 2) + r2;
        float v = acc[mt][nt][r2] + bia;
        if (RELU) v = fmaxf(v, 0.0f);
        if (OUTF32) ((float*)Cv)[(size_t)m * Nd + n] = v;
        else        ((u16*)Cv)[(size_t)m * Nd + n] = f2bf(v);
      }
    }
  }
}

// ---------------- bf16 MFMA GEMM (64x64), async staging, token GEMMs ----------------
template<int RELU, int OUTF32>
__global__ __launch_bounds__(256) void gemm64(const u16* __restrict__ A,
                                              const u16* __restrict__ WT,
                                              const float* __restrict__ bias,
                                              void* __restrict__ Cv,
                                              int Kd, int Nd){
  __shared__ u16 As[64][32];
  __shared__ u16 Bs[64][32];
  const int t = threadIdx.x;
  const int bm = blockIdx.y << 6;
  const int bn = blockIdx.x << 6;
  const int wave = t >> 6;
  const int lane = t & 63;
  const int wm = (wave & 1) << 5;
  const int wn = (wave >> 1) << 5;
  const int lm = lane & 15;
  const int lk = (lane >> 4) << 3;
  u16* AsF = &As[0][0];
  u16* BsF = &Bs[0][0];
  const int wbase = wave << 6;
  f32x4 acc[2][2] = {};
  for (int k0 = 0; k0 < Kd; k0 += 32){
    {
      int r = t >> 2;
      int c = (t & 3) << 3;
      int dst = wbase << 3;
      ld_g2l(A  + (size_t)(bm + r) * Kd + k0 + c, AsF + dst);
      ld_g2l(WT + (size_t)(bn + r) * Kd + k0 + c, BsF + dst);
    }
    __syncthreads();
    short8 af[2], bfr[2];
#pragma unroll
    for (int mt = 0; mt < 2; mt++) af[mt] = *(const short8*)&As[wm + (mt << 4) + lm][lk];
#pragma unroll
    for (int nt = 0; nt < 2; nt++) bfr[nt] = *(const short8*)&Bs[wn + (nt << 4) + lm][lk];
#pragma unroll
    for (int mt = 0; mt < 2; mt++)
#pragma unroll
      for (int nt = 0; nt < 2; nt++)
        acc[mt][nt] = __builtin_amdgcn_mfma_f32_16x16x32_bf16(af[mt], bfr[nt], acc[mt][nt], 0, 0, 0);
    __syncthreads();
  }
#pragma unroll
  for (int nt = 0; nt < 2; nt++){
    int n = bn + wn + (nt << 4) + lm;
    float bia = bias[n];
#pragma unroll
    for (int mt = 0; mt < 2; mt++){
#pragma unroll
      for (int r2 = 0; r2 < 4; r2++){
        int m = bm + wm + (mt << 4) + ((lane >> 4) << 2) + r2;
        float v = acc[mt][nt][r2] + bia;
        if (RELU) v = fmaxf(v, 0.0f);
        if (OUTF32) ((float*)Cv)[(size_t)m * Nd + n] = v;
        else        ((u16*)Cv)[(size_t)m * Nd + n] = f2bf(v);
      }
    }
  }
}

// ---------------- GEMM + fused max-pool (128x128), async staging ----------------
__global__ __launch_bounds__(256) void gemm_pool(const u16* __restrict__ A,
                                                 const u16* __restrict__ WT,
                                                 const float* __restrict__ bias,
                                                 u16* __restrict__ pooled,
                                                 int Kd, int Nd, int groupBase){
  __shared__ u16 As[128][32];
  __shared__ u16 Bs[128][32];
  const int t = threadIdx.x;
  const int bm = blockIdx.y << 7;
  const int bn = blockIdx.x << 7;
  const int wave = t >> 6;
  const int lane = t & 63;
  const int wm = (wave & 1) << 6;
  const int wn = (wave >> 1) << 6;
  const int lm = lane & 15;
  const int lk = (lane >> 4) << 3;
  u16* AsF = &As[0][0];
  u16* BsF = &Bs[0][0];
  const int wbase = wave << 6;
  f32x4 acc[4][4] = {};
  for (int k0 = 0; k0 < Kd; k0 += 32){
#pragma unroll
    for (int it = 0; it < 2; it++){
      int slot = t + (it << 8);
      int r = slot >> 2;
      int c = (slot & 3) << 3;
      int dst = (wbase + (it << 8)) << 3;
      ld_g2l(A  + (size_t)(bm + r) * Kd + k0 + c, AsF + dst);
      ld_g2l(WT + (size_t)(bn + r) * Kd + k0 + c, BsF + dst);
    }
    __syncthreads();
    short8 af[4], bfr[4];
#pragma unroll
    for (int mt = 0; mt < 4; mt++) af[mt] = *(const short8*)&As[wm + (mt << 4) + lm][lk];
#pragma unroll
    for (int nt = 0; nt < 4; nt++) bfr[nt] = *(const short8*)&Bs[wn + (nt << 4) + lm][lk];
#pragma unroll
    for (int mt = 0; mt < 4; mt++)
#pragma unroll
      for (int nt = 0; nt < 4; nt++)
        acc[mt][nt] = __builtin_amdgcn_mfma_f32_16x16x32_bf16(af[mt], bfr[nt], acc[mt][nt], 0, 0, 0);
    __syncthreads();
  }
  // each (mt) tile's 16 rows are exactly one pooling group
#pragma unroll
  for (int nt = 0; nt < 4; nt++){
    int n = bn + wn + (nt << 4) + lm;
    float bia = bias[n];
#pragma unroll
    for (int mt = 0; mt < 4; mt++){
      f32x4 a = acc[mt][nt];
      float v = fmaxf(fmaxf(a[0], a[1]), fmaxf(a[2], a[3]));
      v = fmaxf(v, __shfl_xor(v, 16));
      v = fmaxf(v, __shfl_xor(v, 32));
      if ((lane >> 4) == 0){
        int g = groupBase + (bm >> 4) + (wm >> 4) + mt;
        pooled[(size_t)g * Nd + n] = f2bf(v + bia);
      }
    }
  }
}

// ---------------- tier fallback (f32) ----------------
__global__ __launch_bounds__(256) void fill_diag(float* __restrict__ out, size_t out_elems){
  size_t i = (size_t)blockIdx.x * 256 + threadIdx.x;
  if (i >= out_elems) return;
  size_t maskStart = (size_t)B_ * M_ * D_ + (size_t)B_ * M_ * 4;
  out[i] = (i >= maskStart) ? 1.0f : 0.0f;
}

extern "C" void kernel_launch(void* const* d_in, const int* in_sizes, int n_in,
                              void* d_out, int out_size, void* d_ws, size_t ws_size,
                              hipStream_t stream){
  (void)in_sizes; (void)n_in;
  const float* coords   = (const float*)d_in[0];
  const float* features = (const float*)d_in[1];
  const float* W0 = (const float*)d_in[2];  const float* b0 = (const float*)d_in[3];
  const float* W1 = (const float*)d_in[4];  const float* b1 = (const float*)d_in[5];
  const float* W2 = (const float*)d_in[6];  const float* b2 = (const float*)d_in[7];
  const float* W3 = (const float*)d_in[8];  const float* b3 = (const float*)d_in[9];
  const float* Wn0 = (const float*)d_in[10]; const float* bn0 = (const float*)d_in[11];
  const float* Wn1 = (const float*)d_in[12]; const float* bn1 = (const float*)d_in[13];
  float* out = (float*)d_out;
  const size_t out_elems = (size_t)out_size;

  char* ws = (char*)d_ws;
  const size_t o_cent = 0;            // 16,384 (FPS order)
  const size_t o_cntS = 16384;        // 16,384 (time order)
  const size_t o_knn  = 32768;        // 65,536 -> 98,304
  const size_t o_Wb   = 131072;       // 4,587,520 bf16 W1t..Wn1t (transposed)
  const size_t o_pool = 4718592;      // 1,572,864 bf16 [1024,768]
  const size_t o_t1   = 6291456;      // 1,572,864
  const size_t o_chunk= 7864320;      // regA (R*1536 B) + regB (R*1024 B)
  const int ROWS = B_ * M_ * K_;      // 16384

  int R = 16384;
  while (R > 128 && o_chunk + (size_t)R * 2560 > ws_size) R >>= 1;
  if (d_ws == nullptr || o_chunk + (size_t)R * 2560 > ws_size){
    fill_diag<<<(int)((out_elems + 255) / 256), 256, 0, stream>>>(out, out_elems);
    return;
  }

  float* cent_fps    = (float*)(ws + o_cent);
  float* cent_sorted = (float*)(ws + o_cntS);
  int*   knn         = (int*)(ws + o_knn);
  u16* Wb   = (u16*)(ws + o_Wb);
  u16* W1t  = Wb;               u16* W2t  = Wb + 131072;
  u16* W3t  = Wb + 524288;      u16* Wn0t = Wb + 1114112;
  u16* Wn1t = Wb + 1703936;
  u16* pooled = (u16*)(ws + o_pool);
  u16* t1     = (u16*)(ws + o_t1);
  u16* regA   = (u16*)(ws + o_chunk);                      // h1 [R,256] then h3 [R,768]
  u16* regB   = (u16*)(ws + o_chunk + (size_t)R * 1536);   // h2 [R,512]

  conv_all<<<560, 256, 0, stream>>>(W1, W2, W3, Wn0, Wn1, Wb);
  fps_block<<<B_, 512, 0, stream>>>(coords, cent_fps);
  rank_scatter<<<B_, 128, 0, stream>>>(cent_fps, cent_sorted, out, out_elems);
  knn_kernel<<<B_ * M_, KNT, 0, stream>>>(coords, cent_sorted, knn);

  for (int rowBase = 0; rowBase < ROWS; rowBase += R){
    gather_l0<<<R / 32, 256, 0, stream>>>(features, knn, W0, b0, regA, rowBase);
    gemm_bf16<1,0><<<dim3(4, R / 128), 256, 0, stream>>>(regA, W1t, b1, regB, 256, 512);
    gemm_bf16<1,0><<<dim3(6, R / 128), 256, 0, stream>>>(regB, W2t, b2, regA, 512, 768);
    gemm_pool<<<dim3(6, R / 128), 256, 0, stream>>>(regA, W3t, b3, pooled, 768, 768, rowBase >> 4);
  }

  gemm64<1,0><<<dim3(12, (B_ * M_) / 64), 256, 0, stream>>>(pooled, Wn0t, bn0, t1, 768, 768);
  gemm64<0,1><<<dim3(12, (B_ * M_) / 64), 256, 0, stream>>>(t1, Wn1t, bn1, out, 768, 768);
}

// Round 7
// 506.109 us; speedup vs baseline: 1.2287x; 1.0281x over previous
//
#include <hip/hip_runtime.h>

#define B_ 8
#define N_ 16384
#define F_ 6
#define M_ 128
#define K_ 16
#define D_ 768

typedef unsigned short u16;
typedef unsigned int u32;
typedef unsigned long long u64;
typedef __attribute__((ext_vector_type(8))) short short8;
typedef __attribute__((ext_vector_type(4))) float f32x4;
typedef __attribute__((ext_vector_type(2))) float f32x2;

__device__ __forceinline__ u16 f2bf(float f){
  union { float f; u32 i; } v; v.f = f;
  u32 x = v.i;
  u32 r = x + 0x7FFFu + ((x >> 16) & 1u);
  return (u16)(r >> 16);
}

// async 16B global->LDS (dest = wave-uniform base + lane*16)
__device__ __forceinline__ void ld_g2l(const u16* g, u16* l){
  __builtin_amdgcn_global_load_lds((const __attribute__((address_space(1))) u32*)g,
                                   (__attribute__((address_space(3))) u32*)l, 16, 0, 0);
}

// packed dual-f32 ops (CDNA2+ full-rate packed fp32; bit-exact IEEE per lane)
__device__ __forceinline__ f32x2 pkadd(f32x2 a, f32x2 b){
  f32x2 d; asm("v_pk_add_f32 %0, %1, %2" : "=v"(d) : "v"(a), "v"(b)); return d;
}
__device__ __forceinline__ f32x2 pkmul(f32x2 a, f32x2 b){
  f32x2 d; asm("v_pk_mul_f32 %0, %1, %2" : "=v"(d) : "v"(a), "v"(b)); return d;
}

// VOLATILE asm 16B load: LLVM cannot duplicate/re-execute a volatile asm, so the
// result MUST stay resident in VGPRs (or spill to scratch — visible in WRITE_SIZE).
// This is the hammer for rounds 0-6's silent re-load-every-step of the FPS state
// (VGPR_Count 92 vs 160 needed; step time == L2-reread BW floor ~4100cy).
__device__ __forceinline__ f32x4 ld_x4(const float* p){
  f32x4 r;
  asm volatile("global_load_dwordx4 %0, %1, off" : "=v"(r) : "v"(p) : "memory");
  return r;
}

// DPP self-max step: v = max(v, lane-shifted v). Full-rate VALU — no LDS, no lgkmcnt.
template<int CTRL>
__device__ __forceinline__ float dppmax(float v){
  union { float f; int i; } a, r;
  a.f = v;
  r.i = __builtin_amdgcn_update_dpp(a.i, a.i, CTRL, 0xF, 0xF, false);
  return fmaxf(v, r.f);
}

// ---------------- all weights f32 -> bf16 transposed [n][k], ONE kernel ----------------
__global__ __launch_bounds__(256) void conv_all(const float* __restrict__ W1,
                                                const float* __restrict__ W2,
                                                const float* __restrict__ W3,
                                                const float* __restrict__ Wn0,
                                                const float* __restrict__ Wn1,
                                                u16* __restrict__ Wb){
  __shared__ u16 tile[64][65];
  int blk = blockIdx.x;
  const float* W; u16* WT; int K, N, lb;
  if      (blk < 32)  { W = W1;  WT = Wb;           K = 256; N = 512; lb = blk; }
  else if (blk < 128) { W = W2;  WT = Wb + 131072;  K = 512; N = 768; lb = blk - 32; }
  else if (blk < 272) { W = W3;  WT = Wb + 524288;  K = 768; N = 768; lb = blk - 128; }
  else if (blk < 416) { W = Wn0; WT = Wb + 1114112; K = 768; N = 768; lb = blk - 272; }
  else                { W = Wn1; WT = Wb + 1703936; K = 768; N = 768; lb = blk - 416; }
  int tiles_n = N >> 6;
  int tk = lb / tiles_n, tn = lb % tiles_n;
  int k0 = tk << 6, n0 = tn << 6;
  int t = threadIdx.x;
#pragma unroll
  for (int q = 0; q < 16; q++){
    int idx = q * 256 + t;
    int kk = idx >> 6, nn = idx & 63;
    tile[kk][nn] = f2bf(W[(size_t)(k0 + kk) * N + n0 + nn]);
  }
  __syncthreads();
#pragma unroll
  for (int q = 0; q < 16; q++){
    int idx = q * 256 + t;
    int nn = idx >> 6, kk = idx & 63;
    WT[(size_t)(n0 + nn) * K + k0 + kk] = tile[kk][nn];
  }
}

// ---------------- FPS: state pinned in VGPRs via volatile-asm loads ----------------
// Thread t owns CONTIGUOUS points [32t, 32t+32) -> lane order == index order; tie-breaks
// (first-max, lowest index == jnp.argmax) resolve by lowest-lane ballot / lowest wave.
// Exact semantics: d = ((dx*dx + dy*dy) + dz*dz) + dw*dw (contract off), md = min(md, d).
// p[k] = (x,y,z,w) from one dwordx4; pk ops on aligned (x,y)/(z,w) halves, scalar adds
// in reference order. waves_per_eu(2,2) grants the 256-VGPR budget the state needs.
__global__ __launch_bounds__(512) __attribute__((amdgpu_waves_per_eu(2, 2)))
void fps_block(const float* __restrict__ coords, float* __restrict__ cent){
#pragma clang fp contract(off)
  __shared__ float swv[2][8];
  __shared__ int   swi[2][8];
  int b = blockIdx.x;
  int t = threadIdx.x;
  int lane = t & 63, wave = t >> 6;
  const float* cb = coords + (size_t)b * N_ * 5;
  const int base = t << 5;                       // first point index owned by this thread
  f32x4 p[32];
#pragma unroll
  for (int k = 0; k < 32; k++){
    p[k] = ld_x4(cb + (size_t)(base + k) * 5 + 1);   // (x,y,z,w) of point base+k
  }
  float md[32];
#pragma unroll
  for (int k = 0; k < 32; k++) md[k] = 1e30f;
  asm volatile("s_waitcnt vmcnt(0)" ::: "memory");   // drain the asm loads
  __builtin_amdgcn_sched_barrier(0);                 // rule #18: pin uses after the wait
  float cx = cb[1], cy = cb[2], cz = cb[3], ct = cb[4];
  if (t == 0){
    float* c0 = cent + (size_t)b * M_ * 4;
    c0[0]=cx; c0[1]=cy; c0[2]=cz; c0[3]=ct;
  }
  for (int step = 1; step < M_; step++){
    // x - c computed as x + (-c): IEEE-identical, enables plain v_pk_add
    f32x2 ncxy = (f32x2){-cx, -cy};
    f32x2 nczw = (f32x2){-cz, -ct};
    float bv = -1.0f; int bl = 0;
#pragma unroll
    for (int k = 0; k < 32; k++){
      f32x2 xy = (f32x2){p[k][0], p[k][1]};          // aligned low half of the quad
      f32x2 zw = (f32x2){p[k][2], p[k][3]};          // aligned high half
      f32x2 dxy = pkadd(xy, ncxy);                   // (dx, dy)
      f32x2 dzw = pkadd(zw, nczw);                   // (dz, dw)
      f32x2 s1 = pkmul(dxy, dxy);                    // (dx*dx, dy*dy)
      f32x2 s2 = pkmul(dzw, dzw);                    // (dz*dz, dw*dw)
      float s = ((s1[0] + s1[1]) + s2[0]) + s2[1];   // reference rounding order
      float m = fminf(s, md[k]);
      md[k] = m;
      if (m > bv){ bv = m; bl = k; }                 // ascending-index first-max
    }
    int bi = base + bl;                              // global point index
    // ---- wave argmax: 6 DPP fmax levels -> lane 63 holds wave max ----
    float r = bv;
    r = dppmax<0x111>(r);        // row_shr:1
    r = dppmax<0x112>(r);        // row_shr:2
    r = dppmax<0x114>(r);        // row_shr:4
    r = dppmax<0x118>(r);        // row_shr:8
    r = dppmax<0x142>(r);        // row_bcast:15
    r = dppmax<0x143>(r);        // row_bcast:31
    union { float f; int i; } rm; rm.f = r;
    union { int i; float f; } wmu; wmu.i = __builtin_amdgcn_readlane(rm.i, 63);
    float wmax = wmu.f;                              // uniform (SGPR)
    u64 wmask = __ballot(bv == wmax);
    int srcL = (int)__ffsll((unsigned long long)wmask) - 1;  // lowest lane = lowest index
    int wbi = __builtin_amdgcn_readlane(bi, srcL);   // uniform winner index of this wave
    int par = step & 1;
    if (lane == 0){ swv[par][wave] = wmax; swi[par][wave] = wbi; }
    __syncthreads();                                 // only barrier per step
    // ---- block combine: broadcast LDS reads + uniform serial strict-greater scan ----
    float fv = swv[par][0]; int fi = swi[par][0];
#pragma unroll
    for (int w = 1; w < 8; w++){
      float v = swv[par][w];
      int  iw = swi[par][w];
      if (v > fv){ fv = v; fi = iw; }                // strict > keeps lowest wave (= lowest index)
    }
    int widx = __builtin_amdgcn_readfirstlane(fi);
    size_t wb = (size_t)widx * 5;
    cx = cb[wb+1]; cy = cb[wb+2]; cz = cb[wb+3]; ct = cb[wb+4];
    if (t == 0){
      float* cr = cent + ((size_t)b * M_ + step) * 4;
      cr[0]=cx; cr[1]=cy; cr[2]=cz; cr[3]=ct;
    }
  }
}

// ---------------- stable rank by centroid time; relabel early; f32 outputs ----------------
__global__ __launch_bounds__(128) void rank_scatter(const float* __restrict__ cent_fps,
                                                    float* __restrict__ cent_sorted,
                                                    float* __restrict__ out,
                                                    size_t out_elems){
  int b = blockIdx.x, m = threadIdx.x;
  __shared__ float tt[M_];
  const float* row = cent_fps + ((size_t)b * M_ + m) * 4;
  float x=row[0], y=row[1], z=row[2], w=row[3];
  tt[m] = w;
  __syncthreads();
  int rank = 0;
  for (int j = 0; j < M_; j++){
    float tj = tt[j];
    if (tj < w || (tj == w && j < m)) rank++;       // stable argsort semantics
  }
  float* dst = cent_sorted + ((size_t)b * M_ + rank) * 4;
  dst[0]=x; dst[1]=y; dst[2]=z; dst[3]=w;
  size_t co = (size_t)B_ * M_ * D_ + ((size_t)b * M_ + rank) * 4;
  if (co + 3 < out_elems){
    out[co+0]=x; out[co+1]=y; out[co+2]=z; out[co+3]=w;
  }
  size_t mo = (size_t)B_ * M_ * D_ + (size_t)B_ * M_ * 4 + (size_t)b * M_ + m;
  if (mo < out_elems) out[mo] = 1.0f;              // mask = True -> 1.0f
}

// ---------------- kNN: f32, np op order, stable-min extraction ----------------
#define KNT 512
#define KPT 32
__global__ __launch_bounds__(512) void knn_kernel(const float* __restrict__ coords,
                                                  const float* __restrict__ cent,
                                                  int* __restrict__ knn){
#pragma clang fp contract(off)
  int cm = blockIdx.x;
  int b = cm >> 7;
  const float* cb = coords + (size_t)b * N_ * 5;
  int t = threadIdx.x;
  float cx=cent[cm*4+0], cy=cent[cm*4+1], cz=cent[cm*4+2], ct=cent[cm*4+3];
  float dist[KPT];
#pragma unroll
  for (int j = 0; j < KPT; j++){
    size_t i = t + j * KNT;
    float dx=cb[i*5+1]-cx, dy=cb[i*5+2]-cy, dz=cb[i*5+3]-cz, dw=cb[i*5+4]-ct;
    float d = ((dx*dx + dy*dy) + dz*dz) + dw*dw;
    dist[j] = sqrtf(d);                            // IEEE f32 sqrt = np.sqrt(f32)
  }
  __shared__ float s_wv[8];
  __shared__ int s_wi[8];
  __shared__ int s_bi;
  for (int r = 0; r < K_; r++){
    float bv = 3e38f; int bi = 1 << 30;
#pragma unroll
    for (int j = 0; j < KPT; j++){
      int i = t + j * KNT;
      float v = dist[j];
      if (v < bv){ bv = v; bi = i; }               // first-min kept
    }
#pragma unroll
    for (int off = 32; off > 0; off >>= 1){
      float ov = __shfl_down(bv, off);
      int oi = __shfl_down(bi, off);
      if (ov < bv || (ov == bv && oi < bi)){ bv = ov; bi = oi; }
    }
    if ((t & 63) == 0){ s_wv[t >> 6] = bv; s_wi[t >> 6] = bi; }
    __syncthreads();
    if (t == 0){
      float fv = s_wv[0]; int fi = s_wi[0];
      for (int w = 1; w < 8; w++){
        float wv = s_wv[w]; int wi = s_wi[w];
        if (wv < fv || (wv == fv && wi < fi)){ fv = wv; fi = wi; }
      }
      s_bi = fi;
      knn[(size_t)cm * K_ + r] = fi & (N_ - 1);
    }
    __syncthreads();
    int wi = s_bi;
#pragma unroll
    for (int j = 0; j < KPT; j++){
      if (t + j * KNT == wi) dist[j] = 3e38f;
    }
  }
}

// ---------------- gather + layer0: 32 rows/block, W0/b0/features LDS-staged ----------------
__global__ __launch_bounds__(256) void gather_l0(const float* __restrict__ feat,
                                                 const int* __restrict__ knn,
                                                 const float* __restrict__ W0,
                                                 const float* __restrict__ b0,
                                                 u16* __restrict__ h1,
                                                 int rowBase){
  __shared__ float sW[F_][256];
  __shared__ float sb[256];
  __shared__ float sfa[32][F_];
  int t = threadIdx.x;
#pragma unroll
  for (int k = 0; k < F_; k++) sW[k][t] = W0[k * 256 + t];
  sb[t] = b0[t];
  if (t < 32 * F_){
    int r = t / F_, k = t % F_;
    int grow = rowBase + blockIdx.x * 32 + r;
    int bb = grow >> 11;                          // /(M*K)=2048
    int idx = knn[grow] & (N_ - 1);
    sfa[r][k] = feat[((size_t)bb * N_ + idx) * F_ + k];
  }
  __syncthreads();
#pragma unroll 4
  for (int r = 0; r < 32; r++){
    float acc = sb[t];
#pragma unroll
    for (int k = 0; k < F_; k++) acc = fmaf(sfa[r][k], sW[k][t], acc);
    int lrow = blockIdx.x * 32 + r;
    h1[(size_t)lrow * 256 + t] = f2bf(fmaxf(acc, 0.0f));
  }
}

// ---------------- bf16 MFMA GEMM (128x128), async global->LDS staging ----------------
// Unpadded [128][32] rows (64B): dest = wave-uniform base + lane*16 (m97 layout).
template<int RELU, int OUTF32>
__global__ __launch_bounds__(256) void gemm_bf16(const u16* __restrict__ A,
                                                 const u16* __restrict__ WT,
                                                 const float* __restrict__ bias,
                                                 void* __restrict__ Cv,
                                                 int Kd, int Nd){
  __shared__ u16 As[128][32];
  __shared__ u16 Bs[128][32];
  const int t = threadIdx.x;
  const int bm = blockIdx.y << 7;
  const int bn = blockIdx.x << 7;
  const int wave = t >> 6;
  const int lane = t & 63;
  const int wm = (wave & 1) << 6;
  const int wn = (wave >> 1) << 6;
  const int lm = lane & 15;
  const int lk = (lane >> 4) << 3;
  u16* AsF = &As[0][0];
  u16* BsF = &Bs[0][0];
  const int wbase = wave << 6;               // t - lane
  f32x4 acc[4][4] = {};
  for (int k0 = 0; k0 < Kd; k0 += 32){
#pragma unroll
    for (int it = 0; it < 2; it++){
      int slot = t + (it << 8);
      int r = slot >> 2;
      int c = (slot & 3) << 3;
      int dst = (wbase + (it << 8)) << 3;    // u16 elements; +lane*16B by HW
      ld_g2l(A  + (size_t)(bm + r) * Kd + k0 + c, AsF + dst);
      ld_g2l(WT + (size_t)(bn + r) * Kd + k0 + c, BsF + dst);
    }
    __syncthreads();
    short8 af[4], bfr[4];
#pragma unroll
    for (int mt = 0; mt < 4; mt++) af[mt] = *(const short8*)&As[wm + (mt << 4) + lm][lk];
#pragma unroll
    for (int nt = 0; nt < 4; nt++) bfr[nt] = *(const short8*)&Bs[wn + (nt << 4) + lm][lk];
#pragma unroll
    for (int mt = 0; mt < 4; mt++)
#pragma unroll
      for (int nt = 0; nt < 4; nt++)
        acc[mt][nt] = __builtin_amdgcn_mfma_f32_16x16x32_bf16(af[mt], bfr[nt], acc[mt][nt], 0, 0, 0);
    __syncthreads();
  }
#pragma unroll
  for (int nt = 0; nt < 4; nt++){
    int n = bn + wn + (nt << 4) + lm;
    float bia = bias[n];
#pragma unroll
    for (int mt = 0; mt < 4; mt++){
#pragma unroll
      for (int r2 = 0; r2 < 4; r2++){
        int m = bm + wm + (mt << 4) + ((lane >> 4) << 2) + r2;
        float v = acc[mt][nt][r2] + bia;
        if (RELU) v = fmaxf(v, 0.0f);
        if (OUTF32) ((float*)Cv)[(size_t)m * Nd + n] = v;
        else        ((u16*)Cv)[(size_t)m * Nd + n] = f2bf(v);
      }
    }
  }
}

// ---------------- bf16 MFMA GEMM (64x64), async staging, token GEMMs ----------------
template<int RELU, int OUTF32>
__global__ __launch_bounds__(256) void gemm64(const u16* __restrict__ A,
                                              const u16* __restrict__ WT,
                                              const float* __restrict__ bias,
                                              void* __restrict__ Cv,
                                              int Kd, int Nd){
  __shared__ u16 As[64][32];
  __shared__ u16 Bs[64][32];
  const int t = threadIdx.x;
  const int bm = blockIdx.y << 6;
  const int bn = blockIdx.x << 6;
  const int wave = t >> 6;
  const int lane = t & 63;
  const int wm = (wave & 1) << 5;
  const int wn = (wave >> 1) << 5;
  const int lm = lane & 15;
  const int lk = (lane >> 4) << 3;
  u16* AsF = &As[0][0];
  u16* BsF = &Bs[0][0];
  const int wbase = wave << 6;
  f32x4 acc[2][2] = {};
  for (int k0 = 0; k0 < Kd; k0 += 32){
    {
      int r = t >> 2;
      int c = (t & 3) << 3;
      int dst = wbase << 3;
      ld_g2l(A  + (size_t)(bm + r) * Kd + k0 + c, AsF + dst);
      ld_g2l(WT + (size_t)(bn + r) * Kd + k0 + c, BsF + dst);
    }
    __syncthreads();
    short8 af[2], bfr[2];
#pragma unroll
    for (int mt = 0; mt < 2; mt++) af[mt] = *(const short8*)&As[wm + (mt << 4) + lm][lk];
#pragma unroll
    for (int nt = 0; nt < 2; nt++) bfr[nt] = *(const short8*)&Bs[wn + (nt << 4) + lm][lk];
#pragma unroll
    for (int mt = 0; mt < 2; mt++)
#pragma unroll
      for (int nt = 0; nt < 2; nt++)
        acc[mt][nt] = __builtin_amdgcn_mfma_f32_16x16x32_bf16(af[mt], bfr[nt], acc[mt][nt], 0, 0, 0);
    __syncthreads();
  }
#pragma unroll
  for (int nt = 0; nt < 2; nt++){
    int n = bn + wn + (nt << 4) + lm;
    float bia = bias[n];
#pragma unroll
    for (int mt = 0; mt < 2; mt++){
#pragma unroll
      for (int r2 = 0; r2 < 4; r2++){
        int m = bm + wm + (mt << 4) + ((lane >> 4) << 2) + r2;
        float v = acc[mt][nt][r2] + bia;
        if (RELU) v = fmaxf(v, 0.0f);
        if (OUTF32) ((float*)Cv)[(size_t)m * Nd + n] = v;
        else        ((u16*)Cv)[(size_t)m * Nd + n] = f2bf(v);
      }
    }
  }
}

// ---------------- GEMM + fused max-pool (128x128), async staging ----------------
__global__ __launch_bounds__(256) void gemm_pool(const u16* __restrict__ A,
                                                 const u16* __restrict__ WT,
                                                 const float* __restrict__ bias,
                                                 u16* __restrict__ pooled,
                                                 int Kd, int Nd, int groupBase){
  __shared__ u16 As[128][32];
  __shared__ u16 Bs[128][32];
  const int t = threadIdx.x;
  const int bm = blockIdx.y << 7;
  const int bn = blockIdx.x << 7;
  const int wave = t >> 6;
  const int lane = t & 63;
  const int wm = (wave & 1) << 6;
  const int wn = (wave >> 1) << 6;
  const int lm = lane & 15;
  const int lk = (lane >> 4) << 3;
  u16* AsF = &As[0][0];
  u16* BsF = &Bs[0][0];
  const int wbase = wave << 6;
  f32x4 acc[4][4] = {};
  for (int k0 = 0; k0 < Kd; k0 += 32){
#pragma unroll
    for (int it = 0; it < 2; it++){
      int slot = t + (it << 8);
      int r = slot >> 2;
      int c = (slot & 3) << 3;
      int dst = (wbase + (it << 8)) << 3;
      ld_g2l(A  + (size_t)(bm + r) * Kd + k0 + c, AsF + dst);
      ld_g2l(WT + (size_t)(bn + r) * Kd + k0 + c, BsF + dst);
    }
    __syncthreads();
    short8 af[4], bfr[4];
#pragma unroll
    for (int mt = 0; mt < 4; mt++) af[mt] = *(const short8*)&As[wm + (mt << 4) + lm][lk];
#pragma unroll
    for (int nt = 0; nt < 4; nt++) bfr[nt] = *(const short8*)&Bs[wn + (nt << 4) + lm][lk];
#pragma unroll
    for (int mt = 0; mt < 4; mt++)
#pragma unroll
      for (int nt = 0; nt < 4; nt++)
        acc[mt][nt] = __builtin_amdgcn_mfma_f32_16x16x32_bf16(af[mt], bfr[nt], acc[mt][nt], 0, 0, 0);
    __syncthreads();
  }
  // each (mt) tile's 16 rows are exactly one pooling group
#pragma unroll
  for (int nt = 0; nt < 4; nt++){
    int n = bn + wn + (nt << 4) + lm;
    float bia = bias[n];
#pragma unroll
    for (int mt = 0; mt < 4; mt++){
      f32x4 a = acc[mt][nt];
      float v = fmaxf(fmaxf(a[0], a[1]), fmaxf(a[2], a[3]));
      v = fmaxf(v, __shfl_xor(v, 16));
      v = fmaxf(v, __shfl_xor(v, 32));
      if ((lane >> 4) == 0){
        int g = groupBase + (bm >> 4) + (wm >> 4) + mt;
        pooled[(size_t)g * Nd + n] = f2bf(v + bia);
      }
    }
  }
}

// ---------------- tier fallback (f32) ----------------
__global__ __launch_bounds__(256) void fill_diag(float* __restrict__ out, size_t out_elems){
  size_t i = (size_t)blockIdx.x * 256 + threadIdx.x;
  if (i >= out_elems) return;
  size_t maskStart = (size_t)B_ * M_ * D_ + (size_t)B_ * M_ * 4;
  out[i] = (i >= maskStart) ? 1.0f : 0.0f;
}

extern "C" void kernel_launch(void* const* d_in, const int* in_sizes, int n_in,
                              void* d_out, int out_size, void* d_ws, size_t ws_size,
                              hipStream_t stream){
  (void)in_sizes; (void)n_in;
  const float* coords   = (const float*)d_in[0];
  const float* features = (const float*)d_in[1];
  const float* W0 = (const float*)d_in[2];  const float* b0 = (const float*)d_in[3];
  const float* W1 = (const float*)d_in[4];  const float* b1 = (const float*)d_in[5];
  const float* W2 = (const float*)d_in[6];  const float* b2 = (const float*)d_in[7];
  const float* W3 = (const float*)d_in[8];  const float* b3 = (const float*)d_in[9];
  const float* Wn0 = (const float*)d_in[10]; const float* bn0 = (const float*)d_in[11];
  const float* Wn1 = (const float*)d_in[12]; const float* bn1 = (const float*)d_in[13];
  float* out = (float*)d_out;
  const size_t out_elems = (size_t)out_size;

  char* ws = (char*)d_ws;
  const size_t o_cent = 0;            // 16,384 (FPS order)
  const size_t o_cntS = 16384;        // 16,384 (time order)
  const size_t o_knn  = 32768;        // 65,536 -> 98,304
  const size_t o_Wb   = 131072;       // 4,587,520 bf16 W1t..Wn1t (transposed)
  const size_t o_pool = 4718592;      // 1,572,864 bf16 [1024,768]
  const size_t o_t1   = 6291456;      // 1,572,864
  const size_t o_chunk= 7864320;      // regA (R*1536 B) + regB (R*1024 B)
  const int ROWS = B_ * M_ * K_;      // 16384

  int R = 16384;
  while (R > 128 && o_chunk + (size_t)R * 2560 > ws_size) R >>= 1;
  if (d_ws == nullptr || o_chunk + (size_t)R * 2560 > ws_size){
    fill_diag<<<(int)((out_elems + 255) / 256), 256, 0, stream>>>(out, out_elems);
    return;
  }

  float* cent_fps    = (float*)(ws + o_cent);
  float* cent_sorted = (float*)(ws + o_cntS);
  int*   knn         = (int*)(ws + o_knn);
  u16* Wb   = (u16*)(ws + o_Wb);
  u16* W1t  = Wb;               u16* W2t  = Wb + 131072;
  u16* W3t  = Wb + 524288;      u16* Wn0t = Wb + 1114112;
  u16* Wn1t = Wb + 1703936;
  u16* pooled = (u16*)(ws + o_pool);
  u16* t1     = (u16*)(ws + o_t1);
  u16* regA   = (u16*)(ws + o_chunk);                      // h1 [R,256] then h3 [R,768]
  u16* regB   = (u16*)(ws + o_chunk + (size_t)R * 1536);   // h2 [R,512]

  conv_all<<<560, 256, 0, stream>>>(W1, W2, W3, Wn0, Wn1, Wb);
  fps_block<<<B_, 512, 0, stream>>>(coords, cent_fps);
  rank_scatter<<<B_, 128, 0, stream>>>(cent_fps, cent_sorted, out, out_elems);
  knn_kernel<<<B_ * M_, KNT, 0, stream>>>(coords, cent_sorted, knn);

  for (int rowBase = 0; rowBase < ROWS; rowBase += R){
    gather_l0<<<R / 32, 256, 0, stream>>>(features, knn, W0, b0, regA, rowBase);
    gemm_bf16<1,0><<<dim3(4, R / 128), 256, 0, stream>>>(regA, W1t, b1, regB, 256, 512);
    gemm_bf16<1,0><<<dim3(6, R / 128), 256, 0, stream>>>(regB, W2t, b2, regA, 512, 768);
    gemm_pool<<<dim3(6, R / 128), 256, 0, stream>>>(regA, W3t, b3, pooled, 768, 768, rowBase >> 4);
  }

  gemm64<1,0><<<dim3(12, (B_ * M_) / 64), 256, 0, stream>>>(pooled, Wn0t, bn0, t1, 768, 768);
  gemm64<0,1><<<dim3(12, (B_ * M_) / 64), 256, 0, stream>>>(t1, Wn1t, bn1, out, 768, 768);
}